// Round 4
// baseline (3073.663 us; speedup 1.0000x reference)
//
#include <hip/hip_runtime.h>
#include <hip/hip_bf16.h>
#include <hip/hip_fp16.h>
#include <string.h>

#define N_NODES  200000
#define N_EDGES  6400000
#define N_GRAPHS 512
#define DIM_IN   128
#define HID      32
#define BN_EPS   1e-5f

// chunked scan params
#define CHUNK    2048
#define NCHUNKS  98   // ceil(200000/2048)

typedef const float* fp;

// fp16 storage helpers (RNE via v_cvt_f16_f32 / v_cvt_f32_f16)
__device__ __forceinline__ unsigned short f2h(float f) {
    __half h = __float2half(f);
    unsigned short u; __builtin_memcpy(&u, &h, 2); return u;
}
__device__ __forceinline__ float2 h2f2(unsigned int u) {
    __half2 h; __builtin_memcpy(&h, &u, 4);
    return __half22float2(h);
}

// ---------------- CSR build ----------------

// LDS-binned histogram: 16 node-ranges of 12500 (50KB LDS each), 16 blocks/range.
__global__ __launch_bounds__(256) void k_hist2(const int* __restrict__ dst,
                                               int* __restrict__ deg) {
    __shared__ int lh[12500];  // 50 KB
    const int grp = blockIdx.x & 15;        // node range
    const int blk = blockIdx.x >> 4;        // edge slice [0,16)
    const int lo = grp * 12500;
    for (int j = threadIdx.x; j < 12500; j += 256) lh[j] = 0;
    __syncthreads();
    const int4* d4 = reinterpret_cast<const int4*>(dst) + blk * 100000;
    for (int j = threadIdx.x; j < 100000; j += 256) {
        int4 v = d4[j];
        int a;
        a = v.x - lo; if ((unsigned)a < 12500u) atomicAdd(&lh[a], 1);
        a = v.y - lo; if ((unsigned)a < 12500u) atomicAdd(&lh[a], 1);
        a = v.z - lo; if ((unsigned)a < 12500u) atomicAdd(&lh[a], 1);
        a = v.w - lo; if ((unsigned)a < 12500u) atomicAdd(&lh[a], 1);
    }
    __syncthreads();
    for (int j = threadIdx.x; j < 12500; j += 256) {
        int c = lh[j];
        if (c) atomicAdd(&deg[lo + j], c);
    }
}

__global__ void k_chunksum(const int* __restrict__ deg, int* __restrict__ chunksum) {
    __shared__ int red[256];
    int b = blockIdx.x, t = threadIdx.x;
    int base = b * CHUNK;
    int s = 0;
    for (int k = 0; k < 8; ++k) {
        int i = base + t + k * 256;
        if (i < N_NODES) s += deg[i];
    }
    red[t] = s; __syncthreads();
    for (int off = 128; off > 0; off >>= 1) {
        if (t < off) red[t] += red[t + off];
        __syncthreads();
    }
    if (t == 0) chunksum[b] = red[0];
}

__global__ void k_scanchunks(const int* __restrict__ chunksum, int* __restrict__ chunkoff,
                             int* __restrict__ rowptr) {
    __shared__ int buf[128];
    int t = threadIdx.x;  // 128 threads
    int v = (t < NCHUNKS) ? chunksum[t] : 0;
    buf[t] = v; __syncthreads();
    for (int off = 1; off < 128; off <<= 1) {
        int add = (t >= off) ? buf[t - off] : 0;
        __syncthreads();
        buf[t] += add;
        __syncthreads();
    }
    if (t < NCHUNKS) chunkoff[t] = buf[t] - v;  // exclusive
    if (t == 0) rowptr[N_NODES] = N_EDGES;      // every edge has valid dst
}

__global__ void k_scanfinal(const int* __restrict__ deg, const int* __restrict__ chunkoff,
                            int* __restrict__ rowptr, int* __restrict__ fillpos) {
    __shared__ int tsum[256];
    int b = blockIdx.x, t = threadIdx.x;
    int base = b * CHUNK + t * 8;
    int v[8]; int s = 0;
    for (int k = 0; k < 8; ++k) {
        int i = base + k;
        v[k] = (i < N_NODES) ? deg[i] : 0;
        s += v[k];
    }
    tsum[t] = s; __syncthreads();
    for (int off = 1; off < 256; off <<= 1) {
        int add = (t >= off) ? tsum[t - off] : 0;
        __syncthreads();
        tsum[t] += add;
        __syncthreads();
    }
    int run = tsum[t] - s + chunkoff[b];
    for (int k = 0; k < 8; ++k) {
        int i = base + k;
        if (i < N_NODES) { rowptr[i] = run; fillpos[i] = run; run += v[k]; }
    }
}

// Single-pass fill: read edges ONCE (FETCH 201MB -> ~52MB). Counters showed the
// old 8-range scheme's write locality never materialized (WRITE 361MB = full
// scatter regardless), so the 8x redundant edge reads were pure waste.
__global__ __launch_bounds__(256) void k_fill1(
    const int* __restrict__ src, const int* __restrict__ dst,
    int* __restrict__ fillpos, int* __restrict__ csr)
{
    int tid = blockIdx.x * blockDim.x + threadIdx.x;
    int stride = gridDim.x * blockDim.x;
    const int4* d4 = reinterpret_cast<const int4*>(dst);
    const int4* s4 = reinterpret_cast<const int4*>(src);
    for (int j = tid; j < N_EDGES / 4; j += stride) {
        int4 d = d4[j];
        int4 s = s4[j];
        int p;
        p = atomicAdd(&fillpos[d.x], 1); csr[p] = s.x;
        p = atomicAdd(&fillpos[d.y], 1); csr[p] = s.y;
        p = atomicAdd(&fillpos[d.z], 1); csr[p] = s.z;
        p = atomicAdd(&fillpos[d.w], 1); csr[p] = s.w;
    }
}

__global__ void k_bounds(const int* __restrict__ batch, int* __restrict__ gstart) {
    int g = blockIdx.x * blockDim.x + threadIdx.x;
    if (g > N_GRAPHS) return;
    if (g == N_GRAPHS) { gstart[g] = N_NODES; return; }
    int lo = 0, hi = N_NODES;
    while (lo < hi) {
        int mid = (lo + hi) >> 1;
        if (batch[mid] < g) lo = mid + 1; else hi = mid;
    }
    gstart[g] = lo;
}

// ---------------- Layer-0 pre-projection: y = x @ w1  (128 -> 32) ----------------

__global__ __launch_bounds__(256) void k_proj128(
    const float* __restrict__ x, fp w1, float* __restrict__ y,
    unsigned short* __restrict__ y16)
{
    __shared__ float w1s[DIM_IN * 32];  // 16 KiB
    for (int i = threadIdx.x; i < DIM_IN * 32; i += 256) w1s[i] = w1[i];
    __syncthreads();
    const int lane = threadIdx.x & 63;
    const int c = lane & 31;
    const int srcBase = lane & 32;
    int worker   = (blockIdx.x * blockDim.x + threadIdx.x) >> 5;
    int nworkers = (gridDim.x * blockDim.x) >> 5;
    for (int n = worker; n < N_NODES; n += nworkers) {
        const float* xr = x + (size_t)n * DIM_IN;
        float x0 = xr[c], x1 = xr[32 + c], x2 = xr[64 + c], x3 = xr[96 + c];
        float acc = 0.f;
        #pragma unroll
        for (int k = 0; k < 32; ++k) {
            acc = fmaf(__shfl(x0, srcBase | k, 64), w1s[k * 32 + c], acc);
            acc = fmaf(__shfl(x1, srcBase | k, 64), w1s[(32 + k) * 32 + c], acc);
            acc = fmaf(__shfl(x2, srcBase | k, 64), w1s[(64 + k) * 32 + c], acc);
            acc = fmaf(__shfl(x3, srcBase | k, 64), w1s[(96 + k) * 32 + c], acc);
        }
        y[(size_t)n * 32 + c] = acc;
        y16[(size_t)n * 32 + c] = f2h(acc);
    }
}

// ---------------- Gather with BN fold (dual-row 8B loads) ----------------
// s[n] = sc * (h[n] + sum_{j in N(n)} h[j]) + (deg+1) * sh   (BN affine commutes)
// 16 lanes per node. Per pair of edges: ONE uint2 load per lane — lanes sub<8
// read the even edge's row, lanes sub>=8 the odd edge's row; each lane covers
// 4 channels (4q..4q+3). Halves VMEM + DS(shfl) instr count vs 4B/lane version;
// identical bytes moved, identical fp32 math up to regrouping.

__global__ __launch_bounds__(256) void k_gather8(
    const float* __restrict__ h, const unsigned short* __restrict__ h16,
    const int* __restrict__ rowptr, const int* __restrict__ csr,
    float* __restrict__ sout,
    const float* __restrict__ stats, fp gamma, fp beta)
{
    const int lane = threadIdx.x & 63;
    const int sub  = lane & 15;      // position in 16-lane node group
    const int q    = sub & 7;        // quarter-row slot (uint2 index in row)
    const int hh   = sub >> 3;       // 0: even edges, 1: odd edges
    const int srcBase = lane & 48;   // group base within wave
    // BN affine for this lane's 4 channels c = 4q..4q+3
    float sc0 = 1.f, sc1 = 1.f, sc2 = 1.f, sc3 = 1.f;
    float sh0 = 0.f, sh1 = 0.f, sh2 = 0.f, sh3 = 0.f;
    if (stats) {
        const int c0 = 4 * q;
        float m0 = stats[c0 + 0] * (1.f / N_NODES);
        float m1 = stats[c0 + 1] * (1.f / N_NODES);
        float m2 = stats[c0 + 2] * (1.f / N_NODES);
        float m3 = stats[c0 + 3] * (1.f / N_NODES);
        float v0 = stats[32 + c0 + 0] * (1.f / N_NODES) - m0 * m0;
        float v1 = stats[32 + c0 + 1] * (1.f / N_NODES) - m1 * m1;
        float v2 = stats[32 + c0 + 2] * (1.f / N_NODES) - m2 * m2;
        float v3 = stats[32 + c0 + 3] * (1.f / N_NODES) - m3 * m3;
        sc0 = gamma[c0 + 0] * rsqrtf(v0 + BN_EPS);
        sc1 = gamma[c0 + 1] * rsqrtf(v1 + BN_EPS);
        sc2 = gamma[c0 + 2] * rsqrtf(v2 + BN_EPS);
        sc3 = gamma[c0 + 3] * rsqrtf(v3 + BN_EPS);
        sh0 = beta[c0 + 0] - m0 * sc0;
        sh1 = beta[c0 + 1] - m1 * sc1;
        sh2 = beta[c0 + 2] - m2 * sc2;
        sh3 = beta[c0 + 3] - m3 * sc3;
    }
    const uint2*  hp2 = reinterpret_cast<const uint2*>(h16);  // row = 8 uint2 (64B)
    const float4* hs4 = reinterpret_cast<const float4*>(h);   // row = 8 float4
    float4* so4 = reinterpret_cast<float4*>(sout);
    int worker   = (blockIdx.x * blockDim.x + threadIdx.x) >> 4;
    int nworkers = (gridDim.x * blockDim.x) >> 4;
    for (int n = worker; n < N_NODES; n += nworkers) {
        int e0 = rowptr[n], e1 = rowptr[n + 1];
        float a0 = 0.f, a1 = 0.f, a2 = 0.f, a3 = 0.f;
        int e = e0;
        while (e < e1) {
            int rem = e1 - e;
            int cnt = rem < 16 ? rem : 16;
            int myidx = (sub < cnt) ? csr[e + sub] : 0;
            if (cnt == 16) {
                int i0 = __shfl(myidx, srcBase | (0  + hh), 64);
                int i1 = __shfl(myidx, srcBase | (2  + hh), 64);
                int i2 = __shfl(myidx, srcBase | (4  + hh), 64);
                int i3 = __shfl(myidx, srcBase | (6  + hh), 64);
                int i4 = __shfl(myidx, srcBase | (8  + hh), 64);
                int i5 = __shfl(myidx, srcBase | (10 + hh), 64);
                int i6 = __shfl(myidx, srcBase | (12 + hh), 64);
                int i7 = __shfl(myidx, srcBase | (14 + hh), 64);
                uint2 u0 = hp2[(size_t)i0 * 8 + q];
                uint2 u1 = hp2[(size_t)i1 * 8 + q];
                uint2 u2 = hp2[(size_t)i2 * 8 + q];
                uint2 u3 = hp2[(size_t)i3 * 8 + q];
                uint2 u4 = hp2[(size_t)i4 * 8 + q];
                uint2 u5 = hp2[(size_t)i5 * 8 + q];
                uint2 u6 = hp2[(size_t)i6 * 8 + q];
                uint2 u7 = hp2[(size_t)i7 * 8 + q];
                float2 fA, fB;
                fA = h2f2(u0.x); fB = h2f2(u0.y);
                a0 += fA.x; a1 += fA.y; a2 += fB.x; a3 += fB.y;
                fA = h2f2(u1.x); fB = h2f2(u1.y);
                a0 += fA.x; a1 += fA.y; a2 += fB.x; a3 += fB.y;
                fA = h2f2(u2.x); fB = h2f2(u2.y);
                a0 += fA.x; a1 += fA.y; a2 += fB.x; a3 += fB.y;
                fA = h2f2(u3.x); fB = h2f2(u3.y);
                a0 += fA.x; a1 += fA.y; a2 += fB.x; a3 += fB.y;
                fA = h2f2(u4.x); fB = h2f2(u4.y);
                a0 += fA.x; a1 += fA.y; a2 += fB.x; a3 += fB.y;
                fA = h2f2(u5.x); fB = h2f2(u5.y);
                a0 += fA.x; a1 += fA.y; a2 += fB.x; a3 += fB.y;
                fA = h2f2(u6.x); fB = h2f2(u6.y);
                a0 += fA.x; a1 += fA.y; a2 += fB.x; a3 += fB.y;
                fA = h2f2(u7.x); fB = h2f2(u7.y);
                a0 += fA.x; a1 += fA.y; a2 += fB.x; a3 += fB.y;
            } else {
                int k = 0;
                for (; k + 2 <= cnt; k += 2) {
                    int i = __shfl(myidx, srcBase | (k + hh), 64);
                    uint2 u = hp2[(size_t)i * 8 + q];
                    float2 fA = h2f2(u.x), fB = h2f2(u.y);
                    a0 += fA.x; a1 += fA.y; a2 += fB.x; a3 += fB.y;
                }
                if (k < cnt) {  // odd tail: only half hh==0 contributes
                    int i = __shfl(myidx, srcBase | k, 64);
                    if (hh == 0) {
                        uint2 u = hp2[(size_t)i * 8 + q];
                        float2 fA = h2f2(u.x), fB = h2f2(u.y);
                        a0 += fA.x; a1 += fA.y; a2 += fB.x; a3 += fB.y;
                    }
                }
            }
            e += cnt;
        }
        // combine even/odd halves within the group
        a0 += __shfl_xor(a0, 8, 64);
        a1 += __shfl_xor(a1, 8, 64);
        a2 += __shfl_xor(a2, 8, 64);
        a3 += __shfl_xor(a3, 8, 64);
        // self + BN; write by the hh==0 half (8 lanes x 16B = full 128B row)
        float4 self = hs4[(size_t)n * 8 + q];
        float dc = (float)(e1 - e0 + 1);   // deg + 1 (self)
        float4 o;
        o.x = fmaf(a0 + self.x, sc0, dc * sh0);
        o.y = fmaf(a1 + self.y, sc1, dc * sh1);
        o.z = fmaf(a2 + self.z, sc2, dc * sh2);
        o.w = fmaf(a3 + self.w, sc3, dc * sh3);
        if (hh == 0) so4[(size_t)n * 8 + q] = o;
    }
}

// ---------------- MLP kernels (streaming, fused BN-stats) ----------------
// Write PRE-BN activation a = relu(mlp(s)) to hout (fp32) + h16out (fp16),
// accumulate per-channel sum / sum-of-squares into stats.

__global__ __launch_bounds__(256) void k_mlp32(
    const float* __restrict__ s, fp w1, fp b1, fp w2, fp b2,
    float* __restrict__ hout, unsigned short* __restrict__ h16out,
    float* __restrict__ stats)
{
    const int lane = threadIdx.x & 63;
    const int c = lane & 31;
    const int srcBase = lane & 32;
    float w1r[32], w2r[32];
    #pragma unroll
    for (int k = 0; k < 32; ++k) {
        w1r[k] = w1[k * 32 + c];
        w2r[k] = w2[k * 32 + c];
    }
    const float b1c = b1[c];
    const float b2c = b2[c];
    int worker   = (blockIdx.x * blockDim.x + threadIdx.x) >> 5;
    int nworkers = (gridDim.x * blockDim.x) >> 5;
    float s1 = 0.f, s2 = 0.f;
    for (int n = worker; n < N_NODES; n += nworkers) {
        float sv = s[(size_t)n * 32 + c];
        float acc1 = b1c;
        #pragma unroll
        for (int k = 0; k < 32; ++k)
            acc1 = fmaf(__shfl(sv, srcBase | k, 64), w1r[k], acc1);
        float h3 = fmaxf(acc1, 0.f);
        float acc2 = b2c;
        #pragma unroll
        for (int k = 0; k < 32; ++k)
            acc2 = fmaf(__shfl(h3, srcBase | k, 64), w2r[k], acc2);
        float a = fmaxf(acc2, 0.f);
        hout[(size_t)n * 32 + c] = a;
        h16out[(size_t)n * 32 + c] = f2h(a);
        s1 += a; s2 += a * a;
    }
    s1 += __shfl_xor(s1, 32, 64);
    s2 += __shfl_xor(s2, 32, 64);
    __shared__ float ls1[4][32], ls2[4][32];
    int w = threadIdx.x >> 6;
    if ((threadIdx.x & 32) == 0) { ls1[w][c] = s1; ls2[w][c] = s2; }
    __syncthreads();
    if (threadIdx.x < 32) {
        float t1 = ls1[0][c] + ls1[1][c] + ls1[2][c] + ls1[3][c];
        float t2 = ls2[0][c] + ls2[1][c] + ls2[2][c] + ls2[3][c];
        atomicAdd(&stats[c], t1);
        atomicAdd(&stats[32 + c], t2);
    }
}

// layer-0 variant: s already = (x+agg)@w1, so stage 1 is elementwise.
__global__ __launch_bounds__(256) void k_mlp0(
    const float* __restrict__ s, fp b1, fp w2, fp b2,
    float* __restrict__ hout, unsigned short* __restrict__ h16out,
    float* __restrict__ stats)
{
    const int lane = threadIdx.x & 63;
    const int c = lane & 31;
    const int srcBase = lane & 32;
    float w2r[32];
    #pragma unroll
    for (int k = 0; k < 32; ++k) w2r[k] = w2[k * 32 + c];
    const float b1c = b1[c];
    const float b2c = b2[c];
    int worker   = (blockIdx.x * blockDim.x + threadIdx.x) >> 5;
    int nworkers = (gridDim.x * blockDim.x) >> 5;
    float s1 = 0.f, s2 = 0.f;
    for (int n = worker; n < N_NODES; n += nworkers) {
        float sv = s[(size_t)n * 32 + c];
        float h3 = fmaxf(sv + b1c, 0.f);
        float acc2 = b2c;
        #pragma unroll
        for (int k = 0; k < 32; ++k)
            acc2 = fmaf(__shfl(h3, srcBase | k, 64), w2r[k], acc2);
        float a = fmaxf(acc2, 0.f);
        hout[(size_t)n * 32 + c] = a;
        h16out[(size_t)n * 32 + c] = f2h(a);
        s1 += a; s2 += a * a;
    }
    s1 += __shfl_xor(s1, 32, 64);
    s2 += __shfl_xor(s2, 32, 64);
    __shared__ float ls1[4][32], ls2[4][32];
    int w = threadIdx.x >> 6;
    if ((threadIdx.x & 32) == 0) { ls1[w][c] = s1; ls2[w][c] = s2; }
    __syncthreads();
    if (threadIdx.x < 32) {
        float t1 = ls1[0][c] + ls1[1][c] + ls1[2][c] + ls1[3][c];
        float t2 = ls2[0][c] + ls2[1][c] + ls2[2][c] + ls2[3][c];
        atomicAdd(&stats[c], t1);
        atomicAdd(&stats[32 + c], t2);
    }
}

// decoder last: out = relu(relu(s@w1+b1)@w2_last+b2_last), 32 -> 32 -> 128.
__global__ __launch_bounds__(256) void k_mlp_last(
    const float* __restrict__ s, fp w1, fp b1, fp w2 /*[32][128]*/, fp b2,
    float* __restrict__ out)
{
    const int lane = threadIdx.x & 63;
    const int c = lane & 31;
    float w1r[32], w2a[32], w2b[32];
    #pragma unroll
    for (int k = 0; k < 32; ++k) {
        w1r[k] = w1[k * 32 + c];
        w2a[k] = w2[k * 128 + 2 * lane];
        w2b[k] = w2[k * 128 + 2 * lane + 1];
    }
    const float b1c = b1[c];
    const float b2a = b2[2 * lane];
    const float b2b = b2[2 * lane + 1];
    int worker   = (blockIdx.x * blockDim.x + threadIdx.x) >> 6;
    int nworkers = (gridDim.x * blockDim.x) >> 6;
    for (int n = worker; n < N_NODES; n += nworkers) {
        float sv = s[(size_t)n * 32 + c];  // duplicated across halves
        float acc1 = b1c;
        #pragma unroll
        for (int k = 0; k < 32; ++k)
            acc1 = fmaf(__shfl(sv, k, 64), w1r[k], acc1);
        float h3 = fmaxf(acc1, 0.f);
        float oa = b2a, ob = b2b;
        #pragma unroll
        for (int k = 0; k < 32; ++k) {
            float v = __shfl(h3, (lane & 32) | k, 64);
            oa = fmaf(v, w2a[k], oa);
            ob = fmaf(v, w2b[k], ob);
        }
        oa = fmaxf(oa, 0.f); ob = fmaxf(ob, 0.f);
        float2 pr; pr.x = oa; pr.y = ob;
        reinterpret_cast<float2*>(out)[(size_t)n * 64 + lane] = pr;
    }
}

// Materialize post-BN encoder output once: out = sc*h + sh.
__global__ void k_bnout(const float* __restrict__ h, const float* __restrict__ stats,
                        fp gamma, fp beta, float* __restrict__ out)
{
    const int c = threadIdx.x & 31;
    float m  = stats[c] * (1.f / N_NODES);
    float vv = stats[32 + c] * (1.f / N_NODES) - m * m;
    float sc = gamma[c] * rsqrtf(vv + BN_EPS);
    float sh = beta[c] - m * sc;
    int i = blockIdx.x * blockDim.x + threadIdx.x;
    int stride = gridDim.x * blockDim.x;  // multiple of 32 -> (i&31)==c always
    for (; i < N_NODES * 32; i += stride) out[i] = fmaf(h[i], sc, sh);
}

// Global add-pool of one encoder layer into d_out global_rep slice (batch sorted).
// h holds PRE-BN values; pool of bn(h) = sc * sum(h) + cnt * sh.
__global__ void k_pool(const float* __restrict__ h, const int* __restrict__ gstart,
                       float* __restrict__ out, int col0,
                       const float* __restrict__ stats, fp gamma, fp beta)
{
    int g = blockIdx.x;
    int t = threadIdx.x;
    int f = t & 31, j = t >> 5;  // 8 node-groups x 32 features
    int n0 = gstart[g], n1 = gstart[g + 1];
    float s = 0.f;
    for (int n = n0 + j; n < n1; n += 8) s += h[(size_t)n * 32 + f];
    __shared__ float red[8][32];
    red[j][f] = s; __syncthreads();
    if (t < 32) {
        float tot = 0.f;
        #pragma unroll
        for (int k = 0; k < 8; ++k) tot += red[k][f];
        float m  = stats[f] * (1.f / N_NODES);
        float vv = stats[32 + f] * (1.f / N_NODES) - m * m;
        float sc = gamma[f] * rsqrtf(vv + BN_EPS);
        float sh = beta[f] - m * sc;
        out[g * (5 * HID) + col0 + f] = fmaf(tot, sc, (float)(n1 - n0) * sh);
    }
}

// ---------------- launch ----------------

extern "C" void kernel_launch(void* const* d_in, const int* in_sizes, int n_in,
                              void* d_out, int out_size, void* d_ws, size_t ws_size,
                              hipStream_t stream) {
    fp         x        = (fp)d_in[0];
    const int* edge     = (const int*)d_in[1];
    const int* batch    = (const int*)d_in[2];
    fp e0_w1 = (fp)d_in[3],  e0_b1 = (fp)d_in[4];
    fp e0_w2 = (fp)d_in[5],  e0_b2 = (fp)d_in[6];
    fp enc_w1 = (fp)d_in[7],  enc_b1 = (fp)d_in[8];
    fp enc_w2 = (fp)d_in[9],  enc_b2 = (fp)d_in[10];
    fp enc_gamma = (fp)d_in[11], enc_beta = (fp)d_in[12];
    fp dec_w1 = (fp)d_in[13], dec_b1 = (fp)d_in[14];
    fp dec_w2 = (fp)d_in[15], dec_b2 = (fp)d_in[16];
    fp dec_w2_last = (fp)d_in[17], dec_b2_last = (fp)d_in[18];
    fp dec_gamma = (fp)d_in[19], dec_beta = (fp)d_in[20];

    const int* srcp = edge;            // edge_index[0]
    const int* dstp = edge + N_EDGES;  // edge_index[1]

    float* out_enc    = (float*)d_out;                            // [200000*32]
    float* out_dec    = (float*)d_out + (size_t)N_NODES * 32;     // [200000*128]
    float* out_global = (float*)d_out + (size_t)N_NODES * 160;    // [512*160]

    // workspace carve (256B aligned)
    char* p = (char*)d_ws;
    auto alloc = [&](size_t bytes) -> void* {
        void* r = (void*)p;
        p += (bytes + 255) & ~(size_t)255;
        return r;
    };
    int*   rowptr   = (int*)alloc((N_NODES + 1) * sizeof(int));
    int*   fillpos  = (int*)alloc(N_NODES * sizeof(int));
    int*   deg      = (int*)alloc(N_NODES * sizeof(int));
    int*   chunksum = (int*)alloc(128 * sizeof(int));
    int*   chunkoff = (int*)alloc(128 * sizeof(int));
    int*   gstart   = (int*)alloc((N_GRAPHS + 1) * sizeof(int));
    float* stats    = (float*)alloc(9 * 64 * sizeof(float));
    int*   csr      = (int*)alloc((size_t)N_EDGES * sizeof(int));
    float* hbuf     = (float*)alloc((size_t)N_NODES * 32 * sizeof(float));
    float* sbuf     = (float*)alloc((size_t)N_NODES * 32 * sizeof(float));
    unsigned short* h16 = (unsigned short*)alloc((size_t)N_NODES * 32 * sizeof(unsigned short));

    hipMemsetAsync(deg, 0, N_NODES * sizeof(int), stream);
    hipMemsetAsync(stats, 0, 9 * 64 * sizeof(float), stream);

    // CSR build
    k_hist2<<<256, 256, 0, stream>>>(dstp, deg);
    k_chunksum<<<NCHUNKS, 256, 0, stream>>>(deg, chunksum);
    k_scanchunks<<<1, 128, 0, stream>>>(chunksum, chunkoff, rowptr);
    k_scanfinal<<<NCHUNKS, 256, 0, stream>>>(deg, chunkoff, rowptr, fillpos);
    k_fill1<<<1024, 256, 0, stream>>>(srcp, dstp, fillpos, csr);
    k_bounds<<<3, 256, 0, stream>>>(batch, gstart);

    // ---- Encoder layer 0 (pre-projected; no BN on gather input) ----
    k_proj128<<<1024, 256, 0, stream>>>(x, e0_w1, hbuf, h16);   // hbuf/h16 = y = x@w1
    k_gather8<<<2048, 256, 0, stream>>>(hbuf, h16, rowptr, csr, sbuf,
                                        nullptr, nullptr, nullptr);
    k_mlp0<<<1024, 256, 0, stream>>>(sbuf, e0_b1, e0_w2, e0_b2, hbuf, h16, stats);
    k_pool<<<N_GRAPHS, 256, 0, stream>>>(hbuf, gstart, out_global, 0,
                                         stats, enc_gamma, enc_beta);

    // ---- Encoder layers 1..4 (32 -> 32); gather applies prev layer's BN ----
    for (int i = 0; i < 4; ++i) {
        float* st_prev = stats + i * 64;          // BN stats of h currently in hbuf
        float* st      = stats + (1 + i) * 64;
        k_gather8<<<2048, 256, 0, stream>>>(hbuf, h16, rowptr, csr, sbuf,
                                            st_prev, enc_gamma + i * 32, enc_beta + i * 32);
        k_mlp32<<<1024, 256, 0, stream>>>(sbuf,
                                          enc_w1 + i * 1024, enc_b1 + i * 32,
                                          enc_w2 + i * 1024, enc_b2 + i * 32,
                                          hbuf, h16, st);
        k_pool<<<N_GRAPHS, 256, 0, stream>>>(hbuf, gstart, out_global, (1 + i) * 32,
                                             st, enc_gamma + (1 + i) * 32,
                                             enc_beta + (1 + i) * 32);
    }

    // encoded_rep = bn(enc layer 4 output)
    k_bnout<<<2048, 256, 0, stream>>>(hbuf, stats + 4 * 64,
                                      enc_gamma + 4 * 32, enc_beta + 4 * 32, out_enc);

    // ---- Decoder layers 0..3 (32 -> 32, BN) ----
    for (int i = 0; i < 4; ++i) {
        float* st_prev = (i == 0) ? (stats + 4 * 64) : (stats + (4 + i) * 64);
        fp g_prev      = (i == 0) ? (enc_gamma + 4 * 32) : (dec_gamma + (i - 1) * 32);
        fp b_prev      = (i == 0) ? (enc_beta  + 4 * 32) : (dec_beta  + (i - 1) * 32);
        float* st      = stats + (5 + i) * 64;
        k_gather8<<<2048, 256, 0, stream>>>(hbuf, h16, rowptr, csr, sbuf,
                                            st_prev, g_prev, b_prev);
        k_mlp32<<<1024, 256, 0, stream>>>(sbuf,
                                          dec_w1 + i * 1024, dec_b1 + i * 32,
                                          dec_w2 + i * 1024, dec_b2 + i * 32,
                                          hbuf, h16, st);
    }

    // ---- Decoder layer 4 (32 -> 32 -> 128, relu, no BN) ----
    k_gather8<<<2048, 256, 0, stream>>>(hbuf, h16, rowptr, csr, sbuf,
                                        stats + 8 * 64, dec_gamma + 3 * 32,
                                        dec_beta + 3 * 32);
    k_mlp_last<<<1024, 256, 0, stream>>>(sbuf,
                                         dec_w1 + 4 * 1024, dec_b1 + 4 * 32,
                                         dec_w2_last, dec_b2_last, out_dec);
}

// Round 6
// 2952.677 us; speedup vs baseline: 1.0410x; 1.0410x over previous
//
#include <hip/hip_runtime.h>
#include <hip/hip_bf16.h>
#include <hip/hip_fp16.h>
#include <string.h>

#define N_NODES  200000
#define N_EDGES  6400000
#define N_GRAPHS 512
#define DIM_IN   128
#define HID      32
#define BN_EPS   1e-5f

// chunked scan params
#define CHUNK    2048
#define NCHUNKS  98   // ceil(200000/2048)

typedef const float* fp;

// fp16 storage helpers (RNE via v_cvt_f16_f32 / v_cvt_f32_f16)
__device__ __forceinline__ unsigned short f2h(float f) {
    __half h = __float2half(f);
    unsigned short u; __builtin_memcpy(&u, &h, 2); return u;
}
__device__ __forceinline__ float2 h2f2(unsigned int u) {
    __half2 h; __builtin_memcpy(&h, &u, 4);
    return __half22float2(h);
}

// ---------------- CSR build ----------------

// LDS-binned histogram: 16 node-ranges of 12500 (50KB LDS each), 16 blocks/range.
__global__ __launch_bounds__(256) void k_hist2(const int* __restrict__ dst,
                                               int* __restrict__ deg) {
    __shared__ int lh[12500];  // 50 KB
    const int grp = blockIdx.x & 15;        // node range
    const int blk = blockIdx.x >> 4;        // edge slice [0,16)
    const int lo = grp * 12500;
    for (int j = threadIdx.x; j < 12500; j += 256) lh[j] = 0;
    __syncthreads();
    const int4* d4 = reinterpret_cast<const int4*>(dst) + blk * 100000;
    for (int j = threadIdx.x; j < 100000; j += 256) {
        int4 v = d4[j];
        int a;
        a = v.x - lo; if ((unsigned)a < 12500u) atomicAdd(&lh[a], 1);
        a = v.y - lo; if ((unsigned)a < 12500u) atomicAdd(&lh[a], 1);
        a = v.z - lo; if ((unsigned)a < 12500u) atomicAdd(&lh[a], 1);
        a = v.w - lo; if ((unsigned)a < 12500u) atomicAdd(&lh[a], 1);
    }
    __syncthreads();
    for (int j = threadIdx.x; j < 12500; j += 256) {
        int c = lh[j];
        if (c) atomicAdd(&deg[lo + j], c);
    }
}

__global__ void k_chunksum(const int* __restrict__ deg, int* __restrict__ chunksum) {
    __shared__ int red[256];
    int b = blockIdx.x, t = threadIdx.x;
    int base = b * CHUNK;
    int s = 0;
    for (int k = 0; k < 8; ++k) {
        int i = base + t + k * 256;
        if (i < N_NODES) s += deg[i];
    }
    red[t] = s; __syncthreads();
    for (int off = 128; off > 0; off >>= 1) {
        if (t < off) red[t] += red[t + off];
        __syncthreads();
    }
    if (t == 0) chunksum[b] = red[0];
}

__global__ void k_scanchunks(const int* __restrict__ chunksum, int* __restrict__ chunkoff,
                             int* __restrict__ rowptr) {
    __shared__ int buf[128];
    int t = threadIdx.x;  // 128 threads
    int v = (t < NCHUNKS) ? chunksum[t] : 0;
    buf[t] = v; __syncthreads();
    for (int off = 1; off < 128; off <<= 1) {
        int add = (t >= off) ? buf[t - off] : 0;
        __syncthreads();
        buf[t] += add;
        __syncthreads();
    }
    if (t < NCHUNKS) chunkoff[t] = buf[t] - v;  // exclusive
    if (t == 0) rowptr[N_NODES] = N_EDGES;      // every edge has valid dst
}

__global__ void k_scanfinal(const int* __restrict__ deg, const int* __restrict__ chunkoff,
                            int* __restrict__ rowptr, int* __restrict__ fillpos) {
    __shared__ int tsum[256];
    int b = blockIdx.x, t = threadIdx.x;
    int base = b * CHUNK + t * 8;
    int v[8]; int s = 0;
    for (int k = 0; k < 8; ++k) {
        int i = base + k;
        v[k] = (i < N_NODES) ? deg[i] : 0;
        s += v[k];
    }
    tsum[t] = s; __syncthreads();
    for (int off = 1; off < 256; off <<= 1) {
        int add = (t >= off) ? tsum[t - off] : 0;
        __syncthreads();
        tsum[t] += add;
        __syncthreads();
    }
    int run = tsum[t] - s + chunkoff[b];
    for (int k = 0; k < 8; ++k) {
        int i = base + k;
        if (i < N_NODES) { rowptr[i] = run; fillpos[i] = run; run += v[k]; }
    }
}

// Ranged fill (REVERT of single-pass experiment): grp = blockIdx&7 matches the
// round-robin block->XCD dispatch, so atomics to a 100KB fillpos slice stay
// resident in ONE XCD's L2. Round-4 counters proved this is the win: single-pass
// fill collapsed to VALUBusy 0.19% / 790 GB/s (cross-XCD atomic ping-pong,
// 540us) vs 2.9% / 1890 GB/s (300us) for this scheme. The 8x redundant edge
// reads are the price of L2-local atomics and are mostly L3-absorbed.
// blk0 splits the edge range so each dispatch is ~155us -> fill no longer
// monopolizes the top-5 profile slots (need gather counters).
__global__ __launch_bounds__(256) void k_fill2(
    const int* __restrict__ src, const int* __restrict__ dst,
    int* __restrict__ fillpos, int* __restrict__ csr, int blk0)
{
    const int grp = blockIdx.x & 7;
    const int blk = blk0 + (blockIdx.x >> 3);   // edge slice [blk0, blk0+64)
    const int lo = grp * 25000, hi = lo + 25000;
    const int4* d4 = reinterpret_cast<const int4*>(dst) + blk * 12500;
    const int4* s4 = reinterpret_cast<const int4*>(src) + blk * 12500;
    for (int j = threadIdx.x; j < 12500; j += 256) {
        int4 d = d4[j];
        int4 s = s4[j];
        if (d.x >= lo && d.x < hi) { int p = atomicAdd(&fillpos[d.x], 1); csr[p] = s.x; }
        if (d.y >= lo && d.y < hi) { int p = atomicAdd(&fillpos[d.y], 1); csr[p] = s.y; }
        if (d.z >= lo && d.z < hi) { int p = atomicAdd(&fillpos[d.z], 1); csr[p] = s.z; }
        if (d.w >= lo && d.w < hi) { int p = atomicAdd(&fillpos[d.w], 1); csr[p] = s.w; }
    }
}

__global__ void k_bounds(const int* __restrict__ batch, int* __restrict__ gstart) {
    int g = blockIdx.x * blockDim.x + threadIdx.x;
    if (g > N_GRAPHS) return;
    if (g == N_GRAPHS) { gstart[g] = N_NODES; return; }
    int lo = 0, hi = N_NODES;
    while (lo < hi) {
        int mid = (lo + hi) >> 1;
        if (batch[mid] < g) lo = mid + 1; else hi = mid;
    }
    gstart[g] = lo;
}

// ---------------- Layer-0 pre-projection: y = x @ w1  (128 -> 32) ----------------

__global__ __launch_bounds__(256) void k_proj128(
    const float* __restrict__ x, fp w1, float* __restrict__ y,
    unsigned short* __restrict__ y16)
{
    __shared__ float w1s[DIM_IN * 32];  // 16 KiB
    for (int i = threadIdx.x; i < DIM_IN * 32; i += 256) w1s[i] = w1[i];
    __syncthreads();
    const int lane = threadIdx.x & 63;
    const int c = lane & 31;
    const int srcBase = lane & 32;
    int worker   = (blockIdx.x * blockDim.x + threadIdx.x) >> 5;
    int nworkers = (gridDim.x * blockDim.x) >> 5;
    for (int n = worker; n < N_NODES; n += nworkers) {
        const float* xr = x + (size_t)n * DIM_IN;
        float x0 = xr[c], x1 = xr[32 + c], x2 = xr[64 + c], x3 = xr[96 + c];
        float acc = 0.f;
        #pragma unroll
        for (int k = 0; k < 32; ++k) {
            acc = fmaf(__shfl(x0, srcBase | k, 64), w1s[k * 32 + c], acc);
            acc = fmaf(__shfl(x1, srcBase | k, 64), w1s[(32 + k) * 32 + c], acc);
            acc = fmaf(__shfl(x2, srcBase | k, 64), w1s[(64 + k) * 32 + c], acc);
            acc = fmaf(__shfl(x3, srcBase | k, 64), w1s[(96 + k) * 32 + c], acc);
        }
        y[(size_t)n * 32 + c] = acc;
        y16[(size_t)n * 32 + c] = f2h(acc);
    }
}

// ---------------- Gather with BN fold (dual-row 8B loads) ----------------
// s[n] = sc * (h[n] + sum_{j in N(n)} h[j]) + (deg+1) * sh   (BN affine commutes)
// 16 lanes per node. Per pair of edges: ONE uint2 load per lane — lanes sub<8
// read the even edge's row, lanes sub>=8 the odd edge's row; each lane covers
// 4 channels (4q..4q+3). UNCHANGED this round: need its first clean profile.

__global__ __launch_bounds__(256) void k_gather8(
    const float* __restrict__ h, const unsigned short* __restrict__ h16,
    const int* __restrict__ rowptr, const int* __restrict__ csr,
    float* __restrict__ sout,
    const float* __restrict__ stats, fp gamma, fp beta)
{
    const int lane = threadIdx.x & 63;
    const int sub  = lane & 15;      // position in 16-lane node group
    const int q    = sub & 7;        // quarter-row slot (uint2 index in row)
    const int hh   = sub >> 3;       // 0: even edges, 1: odd edges
    const int srcBase = lane & 48;   // group base within wave
    // BN affine for this lane's 4 channels c = 4q..4q+3
    float sc0 = 1.f, sc1 = 1.f, sc2 = 1.f, sc3 = 1.f;
    float sh0 = 0.f, sh1 = 0.f, sh2 = 0.f, sh3 = 0.f;
    if (stats) {
        const int c0 = 4 * q;
        float m0 = stats[c0 + 0] * (1.f / N_NODES);
        float m1 = stats[c0 + 1] * (1.f / N_NODES);
        float m2 = stats[c0 + 2] * (1.f / N_NODES);
        float m3 = stats[c0 + 3] * (1.f / N_NODES);
        float v0 = stats[32 + c0 + 0] * (1.f / N_NODES) - m0 * m0;
        float v1 = stats[32 + c0 + 1] * (1.f / N_NODES) - m1 * m1;
        float v2 = stats[32 + c0 + 2] * (1.f / N_NODES) - m2 * m2;
        float v3 = stats[32 + c0 + 3] * (1.f / N_NODES) - m3 * m3;
        sc0 = gamma[c0 + 0] * rsqrtf(v0 + BN_EPS);
        sc1 = gamma[c0 + 1] * rsqrtf(v1 + BN_EPS);
        sc2 = gamma[c0 + 2] * rsqrtf(v2 + BN_EPS);
        sc3 = gamma[c0 + 3] * rsqrtf(v3 + BN_EPS);
        sh0 = beta[c0 + 0] - m0 * sc0;
        sh1 = beta[c0 + 1] - m1 * sc1;
        sh2 = beta[c0 + 2] - m2 * sc2;
        sh3 = beta[c0 + 3] - m3 * sc3;
    }
    const uint2*  hp2 = reinterpret_cast<const uint2*>(h16);  // row = 8 uint2 (64B)
    const float4* hs4 = reinterpret_cast<const float4*>(h);   // row = 8 float4
    float4* so4 = reinterpret_cast<float4*>(sout);
    int worker   = (blockIdx.x * blockDim.x + threadIdx.x) >> 4;
    int nworkers = (gridDim.x * blockDim.x) >> 4;
    for (int n = worker; n < N_NODES; n += nworkers) {
        int e0 = rowptr[n], e1 = rowptr[n + 1];
        float a0 = 0.f, a1 = 0.f, a2 = 0.f, a3 = 0.f;
        int e = e0;
        while (e < e1) {
            int rem = e1 - e;
            int cnt = rem < 16 ? rem : 16;
            int myidx = (sub < cnt) ? csr[e + sub] : 0;
            if (cnt == 16) {
                int i0 = __shfl(myidx, srcBase | (0  + hh), 64);
                int i1 = __shfl(myidx, srcBase | (2  + hh), 64);
                int i2 = __shfl(myidx, srcBase | (4  + hh), 64);
                int i3 = __shfl(myidx, srcBase | (6  + hh), 64);
                int i4 = __shfl(myidx, srcBase | (8  + hh), 64);
                int i5 = __shfl(myidx, srcBase | (10 + hh), 64);
                int i6 = __shfl(myidx, srcBase | (12 + hh), 64);
                int i7 = __shfl(myidx, srcBase | (14 + hh), 64);
                uint2 u0 = hp2[(size_t)i0 * 8 + q];
                uint2 u1 = hp2[(size_t)i1 * 8 + q];
                uint2 u2 = hp2[(size_t)i2 * 8 + q];
                uint2 u3 = hp2[(size_t)i3 * 8 + q];
                uint2 u4 = hp2[(size_t)i4 * 8 + q];
                uint2 u5 = hp2[(size_t)i5 * 8 + q];
                uint2 u6 = hp2[(size_t)i6 * 8 + q];
                uint2 u7 = hp2[(size_t)i7 * 8 + q];
                float2 fA, fB;
                fA = h2f2(u0.x); fB = h2f2(u0.y);
                a0 += fA.x; a1 += fA.y; a2 += fB.x; a3 += fB.y;
                fA = h2f2(u1.x); fB = h2f2(u1.y);
                a0 += fA.x; a1 += fA.y; a2 += fB.x; a3 += fB.y;
                fA = h2f2(u2.x); fB = h2f2(u2.y);
                a0 += fA.x; a1 += fA.y; a2 += fB.x; a3 += fB.y;
                fA = h2f2(u3.x); fB = h2f2(u3.y);
                a0 += fA.x; a1 += fA.y; a2 += fB.x; a3 += fB.y;
                fA = h2f2(u4.x); fB = h2f2(u4.y);
                a0 += fA.x; a1 += fA.y; a2 += fB.x; a3 += fB.y;
                fA = h2f2(u5.x); fB = h2f2(u5.y);
                a0 += fA.x; a1 += fA.y; a2 += fB.x; a3 += fB.y;
                fA = h2f2(u6.x); fB = h2f2(u6.y);
                a0 += fA.x; a1 += fA.y; a2 += fB.x; a3 += fB.y;
                fA = h2f2(u7.x); fB = h2f2(u7.y);
                a0 += fA.x; a1 += fA.y; a2 += fB.x; a3 += fB.y;
            } else {
                int k = 0;
                for (; k + 2 <= cnt; k += 2) {
                    int i = __shfl(myidx, srcBase | (k + hh), 64);
                    uint2 u = hp2[(size_t)i * 8 + q];
                    float2 fA = h2f2(u.x), fB = h2f2(u.y);
                    a0 += fA.x; a1 += fA.y; a2 += fB.x; a3 += fB.y;
                }
                if (k < cnt) {  // odd tail: only half hh==0 contributes
                    int i = __shfl(myidx, srcBase | k, 64);
                    if (hh == 0) {
                        uint2 u = hp2[(size_t)i * 8 + q];
                        float2 fA = h2f2(u.x), fB = h2f2(u.y);
                        a0 += fA.x; a1 += fA.y; a2 += fB.x; a3 += fB.y;
                    }
                }
            }
            e += cnt;
        }
        // combine even/odd halves within the group
        a0 += __shfl_xor(a0, 8, 64);
        a1 += __shfl_xor(a1, 8, 64);
        a2 += __shfl_xor(a2, 8, 64);
        a3 += __shfl_xor(a3, 8, 64);
        // self + BN; write by the hh==0 half (8 lanes x 16B = full 128B row)
        float4 self = hs4[(size_t)n * 8 + q];
        float dc = (float)(e1 - e0 + 1);   // deg + 1 (self)
        float4 o;
        o.x = fmaf(a0 + self.x, sc0, dc * sh0);
        o.y = fmaf(a1 + self.y, sc1, dc * sh1);
        o.z = fmaf(a2 + self.z, sc2, dc * sh2);
        o.w = fmaf(a3 + self.w, sc3, dc * sh3);
        if (hh == 0) so4[(size_t)n * 8 + q] = o;
    }
}

// ---------------- MLP kernels (streaming, fused BN-stats) ----------------
// Write PRE-BN activation a = relu(mlp(s)) to hout (fp32) + h16out (fp16),
// accumulate per-channel sum / sum-of-squares into stats.

__global__ __launch_bounds__(256) void k_mlp32(
    const float* __restrict__ s, fp w1, fp b1, fp w2, fp b2,
    float* __restrict__ hout, unsigned short* __restrict__ h16out,
    float* __restrict__ stats)
{
    const int lane = threadIdx.x & 63;
    const int c = lane & 31;
    const int srcBase = lane & 32;
    float w1r[32], w2r[32];
    #pragma unroll
    for (int k = 0; k < 32; ++k) {
        w1r[k] = w1[k * 32 + c];
        w2r[k] = w2[k * 32 + c];
    }
    const float b1c = b1[c];
    const float b2c = b2[c];
    int worker   = (blockIdx.x * blockDim.x + threadIdx.x) >> 5;
    int nworkers = (gridDim.x * blockDim.x) >> 5;
    float s1 = 0.f, s2 = 0.f;
    for (int n = worker; n < N_NODES; n += nworkers) {
        float sv = s[(size_t)n * 32 + c];
        float acc1 = b1c;
        #pragma unroll
        for (int k = 0; k < 32; ++k)
            acc1 = fmaf(__shfl(sv, srcBase | k, 64), w1r[k], acc1);
        float h3 = fmaxf(acc1, 0.f);
        float acc2 = b2c;
        #pragma unroll
        for (int k = 0; k < 32; ++k)
            acc2 = fmaf(__shfl(h3, srcBase | k, 64), w2r[k], acc2);
        float a = fmaxf(acc2, 0.f);
        hout[(size_t)n * 32 + c] = a;
        h16out[(size_t)n * 32 + c] = f2h(a);
        s1 += a; s2 += a * a;
    }
    s1 += __shfl_xor(s1, 32, 64);
    s2 += __shfl_xor(s2, 32, 64);
    __shared__ float ls1[4][32], ls2[4][32];
    int w = threadIdx.x >> 6;
    if ((threadIdx.x & 32) == 0) { ls1[w][c] = s1; ls2[w][c] = s2; }
    __syncthreads();
    if (threadIdx.x < 32) {
        float t1 = ls1[0][c] + ls1[1][c] + ls1[2][c] + ls1[3][c];
        float t2 = ls2[0][c] + ls2[1][c] + ls2[2][c] + ls2[3][c];
        atomicAdd(&stats[c], t1);
        atomicAdd(&stats[32 + c], t2);
    }
}

// layer-0 variant: s already = (x+agg)@w1, so stage 1 is elementwise.
__global__ __launch_bounds__(256) void k_mlp0(
    const float* __restrict__ s, fp b1, fp w2, fp b2,
    float* __restrict__ hout, unsigned short* __restrict__ h16out,
    float* __restrict__ stats)
{
    const int lane = threadIdx.x & 63;
    const int c = lane & 31;
    const int srcBase = lane & 32;
    float w2r[32];
    #pragma unroll
    for (int k = 0; k < 32; ++k) w2r[k] = w2[k * 32 + c];
    const float b1c = b1[c];
    const float b2c = b2[c];
    int worker   = (blockIdx.x * blockDim.x + threadIdx.x) >> 5;
    int nworkers = (gridDim.x * blockDim.x) >> 5;
    float s1 = 0.f, s2 = 0.f;
    for (int n = worker; n < N_NODES; n += nworkers) {
        float sv = s[(size_t)n * 32 + c];
        float h3 = fmaxf(sv + b1c, 0.f);
        float acc2 = b2c;
        #pragma unroll
        for (int k = 0; k < 32; ++k)
            acc2 = fmaf(__shfl(h3, srcBase | k, 64), w2r[k], acc2);
        float a = fmaxf(acc2, 0.f);
        hout[(size_t)n * 32 + c] = a;
        h16out[(size_t)n * 32 + c] = f2h(a);
        s1 += a; s2 += a * a;
    }
    s1 += __shfl_xor(s1, 32, 64);
    s2 += __shfl_xor(s2, 32, 64);
    __shared__ float ls1[4][32], ls2[4][32];
    int w = threadIdx.x >> 6;
    if ((threadIdx.x & 32) == 0) { ls1[w][c] = s1; ls2[w][c] = s2; }
    __syncthreads();
    if (threadIdx.x < 32) {
        float t1 = ls1[0][c] + ls1[1][c] + ls1[2][c] + ls1[3][c];
        float t2 = ls2[0][c] + ls2[1][c] + ls2[2][c] + ls2[3][c];
        atomicAdd(&stats[c], t1);
        atomicAdd(&stats[32 + c], t2);
    }
}

// decoder last: out = relu(relu(s@w1+b1)@w2_last+b2_last), 32 -> 32 -> 128.
__global__ __launch_bounds__(256) void k_mlp_last(
    const float* __restrict__ s, fp w1, fp b1, fp w2 /*[32][128]*/, fp b2,
    float* __restrict__ out)
{
    const int lane = threadIdx.x & 63;
    const int c = lane & 31;
    float w1r[32], w2a[32], w2b[32];
    #pragma unroll
    for (int k = 0; k < 32; ++k) {
        w1r[k] = w1[k * 32 + c];
        w2a[k] = w2[k * 128 + 2 * lane];
        w2b[k] = w2[k * 128 + 2 * lane + 1];
    }
    const float b1c = b1[c];
    const float b2a = b2[2 * lane];
    const float b2b = b2[2 * lane + 1];
    int worker   = (blockIdx.x * blockDim.x + threadIdx.x) >> 6;
    int nworkers = (gridDim.x * blockDim.x) >> 6;
    for (int n = worker; n < N_NODES; n += nworkers) {
        float sv = s[(size_t)n * 32 + c];  // duplicated across halves
        float acc1 = b1c;
        #pragma unroll
        for (int k = 0; k < 32; ++k)
            acc1 = fmaf(__shfl(sv, k, 64), w1r[k], acc1);
        float h3 = fmaxf(acc1, 0.f);
        float oa = b2a, ob = b2b;
        #pragma unroll
        for (int k = 0; k < 32; ++k) {
            float v = __shfl(h3, (lane & 32) | k, 64);
            oa = fmaf(v, w2a[k], oa);
            ob = fmaf(v, w2b[k], ob);
        }
        oa = fmaxf(oa, 0.f); ob = fmaxf(ob, 0.f);
        float2 pr; pr.x = oa; pr.y = ob;
        reinterpret_cast<float2*>(out)[(size_t)n * 64 + lane] = pr;
    }
}

// Materialize post-BN encoder output once: out = sc*h + sh.
__global__ void k_bnout(const float* __restrict__ h, const float* __restrict__ stats,
                        fp gamma, fp beta, float* __restrict__ out)
{
    const int c = threadIdx.x & 31;
    float m  = stats[c] * (1.f / N_NODES);
    float vv = stats[32 + c] * (1.f / N_NODES) - m * m;
    float sc = gamma[c] * rsqrtf(vv + BN_EPS);
    float sh = beta[c] - m * sc;
    int i = blockIdx.x * blockDim.x + threadIdx.x;
    int stride = gridDim.x * blockDim.x;  // multiple of 32 -> (i&31)==c always
    for (; i < N_NODES * 32; i += stride) out[i] = fmaf(h[i], sc, sh);
}

// Global add-pool of one encoder layer into d_out global_rep slice (batch sorted).
// h holds PRE-BN values; pool of bn(h) = sc * sum(h) + cnt * sh.
__global__ void k_pool(const float* __restrict__ h, const int* __restrict__ gstart,
                       float* __restrict__ out, int col0,
                       const float* __restrict__ stats, fp gamma, fp beta)
{
    int g = blockIdx.x;
    int t = threadIdx.x;
    int f = t & 31, j = t >> 5;  // 8 node-groups x 32 features
    int n0 = gstart[g], n1 = gstart[g + 1];
    float s = 0.f;
    for (int n = n0 + j; n < n1; n += 8) s += h[(size_t)n * 32 + f];
    __shared__ float red[8][32];
    red[j][f] = s; __syncthreads();
    if (t < 32) {
        float tot = 0.f;
        #pragma unroll
        for (int k = 0; k < 8; ++k) tot += red[k][f];
        float m  = stats[f] * (1.f / N_NODES);
        float vv = stats[32 + f] * (1.f / N_NODES) - m * m;
        float sc = gamma[f] * rsqrtf(vv + BN_EPS);
        float sh = beta[f] - m * sc;
        out[g * (5 * HID) + col0 + f] = fmaf(tot, sc, (float)(n1 - n0) * sh);
    }
}

// ---------------- launch ----------------

extern "C" void kernel_launch(void* const* d_in, const int* in_sizes, int n_in,
                              void* d_out, int out_size, void* d_ws, size_t ws_size,
                              hipStream_t stream) {
    fp         x        = (fp)d_in[0];
    const int* edge     = (const int*)d_in[1];
    const int* batch    = (const int*)d_in[2];
    fp e0_w1 = (fp)d_in[3],  e0_b1 = (fp)d_in[4];
    fp e0_w2 = (fp)d_in[5],  e0_b2 = (fp)d_in[6];
    fp enc_w1 = (fp)d_in[7],  enc_b1 = (fp)d_in[8];
    fp enc_w2 = (fp)d_in[9],  enc_b2 = (fp)d_in[10];
    fp enc_gamma = (fp)d_in[11], enc_beta = (fp)d_in[12];
    fp dec_w1 = (fp)d_in[13], dec_b1 = (fp)d_in[14];
    fp dec_w2 = (fp)d_in[15], dec_b2 = (fp)d_in[16];
    fp dec_w2_last = (fp)d_in[17], dec_b2_last = (fp)d_in[18];
    fp dec_gamma = (fp)d_in[19], dec_beta = (fp)d_in[20];

    const int* srcp = edge;            // edge_index[0]
    const int* dstp = edge + N_EDGES;  // edge_index[1]

    float* out_enc    = (float*)d_out;                            // [200000*32]
    float* out_dec    = (float*)d_out + (size_t)N_NODES * 32;     // [200000*128]
    float* out_global = (float*)d_out + (size_t)N_NODES * 160;    // [512*160]

    // workspace carve (256B aligned)
    char* p = (char*)d_ws;
    auto alloc = [&](size_t bytes) -> void* {
        void* r = (void*)p;
        p += (bytes + 255) & ~(size_t)255;
        return r;
    };
    int*   rowptr   = (int*)alloc((N_NODES + 1) * sizeof(int));
    int*   fillpos  = (int*)alloc(N_NODES * sizeof(int));
    int*   deg      = (int*)alloc(N_NODES * sizeof(int));
    int*   chunksum = (int*)alloc(128 * sizeof(int));
    int*   chunkoff = (int*)alloc(128 * sizeof(int));
    int*   gstart   = (int*)alloc((N_GRAPHS + 1) * sizeof(int));
    float* stats    = (float*)alloc(9 * 64 * sizeof(float));
    int*   csr      = (int*)alloc((size_t)N_EDGES * sizeof(int));
    float* hbuf     = (float*)alloc((size_t)N_NODES * 32 * sizeof(float));
    float* sbuf     = (float*)alloc((size_t)N_NODES * 32 * sizeof(float));
    unsigned short* h16 = (unsigned short*)alloc((size_t)N_NODES * 32 * sizeof(unsigned short));

    hipMemsetAsync(deg, 0, N_NODES * sizeof(int), stream);
    hipMemsetAsync(stats, 0, 9 * 64 * sizeof(float), stream);

    // CSR build (fill split into 2 half-dispatches for profiler visibility)
    k_hist2<<<256, 256, 0, stream>>>(dstp, deg);
    k_chunksum<<<NCHUNKS, 256, 0, stream>>>(deg, chunksum);
    k_scanchunks<<<1, 128, 0, stream>>>(chunksum, chunkoff, rowptr);
    k_scanfinal<<<NCHUNKS, 256, 0, stream>>>(deg, chunkoff, rowptr, fillpos);
    k_fill2<<<512, 256, 0, stream>>>(srcp, dstp, fillpos, csr, 0);
    k_fill2<<<512, 256, 0, stream>>>(srcp, dstp, fillpos, csr, 64);
    k_bounds<<<3, 256, 0, stream>>>(batch, gstart);

    // ---- Encoder layer 0 (pre-projected; no BN on gather input) ----
    k_proj128<<<1024, 256, 0, stream>>>(x, e0_w1, hbuf, h16);   // hbuf/h16 = y = x@w1
    k_gather8<<<2048, 256, 0, stream>>>(hbuf, h16, rowptr, csr, sbuf,
                                        nullptr, nullptr, nullptr);
    k_mlp0<<<1024, 256, 0, stream>>>(sbuf, e0_b1, e0_w2, e0_b2, hbuf, h16, stats);
    k_pool<<<N_GRAPHS, 256, 0, stream>>>(hbuf, gstart, out_global, 0,
                                         stats, enc_gamma, enc_beta);

    // ---- Encoder layers 1..4 (32 -> 32); gather applies prev layer's BN ----
    for (int i = 0; i < 4; ++i) {
        float* st_prev = stats + i * 64;          // BN stats of h currently in hbuf
        float* st      = stats + (1 + i) * 64;
        k_gather8<<<2048, 256, 0, stream>>>(hbuf, h16, rowptr, csr, sbuf,
                                            st_prev, enc_gamma + i * 32, enc_beta + i * 32);
        k_mlp32<<<1024, 256, 0, stream>>>(sbuf,
                                          enc_w1 + i * 1024, enc_b1 + i * 32,
                                          enc_w2 + i * 1024, enc_b2 + i * 32,
                                          hbuf, h16, st);
        k_pool<<<N_GRAPHS, 256, 0, stream>>>(hbuf, gstart, out_global, (1 + i) * 32,
                                             st, enc_gamma + (1 + i) * 32,
                                             enc_beta + (1 + i) * 32);
    }

    // encoded_rep = bn(enc layer 4 output)
    k_bnout<<<2048, 256, 0, stream>>>(hbuf, stats + 4 * 64,
                                      enc_gamma + 4 * 32, enc_beta + 4 * 32, out_enc);

    // ---- Decoder layers 0..3 (32 -> 32, BN) ----
    for (int i = 0; i < 4; ++i) {
        float* st_prev = (i == 0) ? (stats + 4 * 64) : (stats + (4 + i) * 64);
        fp g_prev      = (i == 0) ? (enc_gamma + 4 * 32) : (dec_gamma + (i - 1) * 32);
        fp b_prev      = (i == 0) ? (enc_beta  + 4 * 32) : (dec_beta  + (i - 1) * 32);
        float* st      = stats + (5 + i) * 64;
        k_gather8<<<2048, 256, 0, stream>>>(hbuf, h16, rowptr, csr, sbuf,
                                            st_prev, g_prev, b_prev);
        k_mlp32<<<1024, 256, 0, stream>>>(sbuf,
                                          dec_w1 + i * 1024, dec_b1 + i * 32,
                                          dec_w2 + i * 1024, dec_b2 + i * 32,
                                          hbuf, h16, st);
    }

    // ---- Decoder layer 4 (32 -> 32 -> 128, relu, no BN) ----
    k_gather8<<<2048, 256, 0, stream>>>(hbuf, h16, rowptr, csr, sbuf,
                                        stats + 8 * 64, dec_gamma + 3 * 32,
                                        dec_beta + 3 * 32);
    k_mlp_last<<<1024, 256, 0, stream>>>(sbuf,
                                         dec_w1 + 4 * 1024, dec_b1 + 4 * 32,
                                         dec_w2_last, dec_b2_last, out_dec);
}

// Round 8
// 2805.860 us; speedup vs baseline: 1.0954x; 1.0523x over previous
//
#include <hip/hip_runtime.h>
#include <hip/hip_bf16.h>
#include <hip/hip_fp16.h>
#include <string.h>

#define N_NODES  200000
#define N_EDGES  6400000
#define N_GRAPHS 512
#define DIM_IN   128
#define HID      32
#define BN_EPS   1e-5f

// chunked scan params
#define CHUNK    2048
#define NCHUNKS  98   // ceil(200000/2048)

typedef const float* fp;

// fp16 storage helpers (RNE via v_cvt_f16_f32 / v_cvt_f32_f16)
__device__ __forceinline__ unsigned short f2h(float f) {
    __half h = __float2half(f);
    unsigned short u; __builtin_memcpy(&u, &h, 2); return u;
}
__device__ __forceinline__ float2 h2f2(unsigned int u) {
    __half2 h; __builtin_memcpy(&h, &u, 4);
    return __half22float2(h);
}

// ---------------- CSR build ----------------

// LDS-binned histogram: 16 node-ranges of 12500 (50KB LDS each), 32 blocks/range.
// Round-6 counters: grid=256 capped occupancy at 1 block/CU (11.7%), VALUBusy
// 4.6%, 527 GB/s -> latency-bound. Fix: grid 512 (2 blocks/CU, 8 waves) + 4-way
// ILP (4 independent int4 loads per iteration before the atomics).
__global__ __launch_bounds__(256) void k_hist2(const int* __restrict__ dst,
                                               int* __restrict__ deg) {
    __shared__ int lh[12500];  // 50 KB
    const int grp = blockIdx.x & 15;        // node range [0,16)
    const int blk = blockIdx.x >> 4;        // edge slice [0,32)
    const int lo = grp * 12500;
    for (int j = threadIdx.x; j < 12500; j += 256) lh[j] = 0;
    __syncthreads();
    // slice = 50000 int4 = 200K edges, processed as 4 sub-segments of 12500 int4
    const int4* d4 = reinterpret_cast<const int4*>(dst) + blk * 50000;
    for (int j = threadIdx.x; j < 12500; j += 256) {
        int4 v0 = d4[j];
        int4 v1 = d4[j + 12500];
        int4 v2 = d4[j + 25000];
        int4 v3 = d4[j + 37500];
        int a;
        a = v0.x - lo; if ((unsigned)a < 12500u) atomicAdd(&lh[a], 1);
        a = v0.y - lo; if ((unsigned)a < 12500u) atomicAdd(&lh[a], 1);
        a = v0.z - lo; if ((unsigned)a < 12500u) atomicAdd(&lh[a], 1);
        a = v0.w - lo; if ((unsigned)a < 12500u) atomicAdd(&lh[a], 1);
        a = v1.x - lo; if ((unsigned)a < 12500u) atomicAdd(&lh[a], 1);
        a = v1.y - lo; if ((unsigned)a < 12500u) atomicAdd(&lh[a], 1);
        a = v1.z - lo; if ((unsigned)a < 12500u) atomicAdd(&lh[a], 1);
        a = v1.w - lo; if ((unsigned)a < 12500u) atomicAdd(&lh[a], 1);
        a = v2.x - lo; if ((unsigned)a < 12500u) atomicAdd(&lh[a], 1);
        a = v2.y - lo; if ((unsigned)a < 12500u) atomicAdd(&lh[a], 1);
        a = v2.z - lo; if ((unsigned)a < 12500u) atomicAdd(&lh[a], 1);
        a = v2.w - lo; if ((unsigned)a < 12500u) atomicAdd(&lh[a], 1);
        a = v3.x - lo; if ((unsigned)a < 12500u) atomicAdd(&lh[a], 1);
        a = v3.y - lo; if ((unsigned)a < 12500u) atomicAdd(&lh[a], 1);
        a = v3.z - lo; if ((unsigned)a < 12500u) atomicAdd(&lh[a], 1);
        a = v3.w - lo; if ((unsigned)a < 12500u) atomicAdd(&lh[a], 1);
    }
    __syncthreads();
    for (int j = threadIdx.x; j < 12500; j += 256) {
        int c = lh[j];
        if (c) atomicAdd(&deg[lo + j], c);
    }
}

__global__ void k_chunksum(const int* __restrict__ deg, int* __restrict__ chunksum) {
    __shared__ int red[256];
    int b = blockIdx.x, t = threadIdx.x;
    int base = b * CHUNK;
    int s = 0;
    for (int k = 0; k < 8; ++k) {
        int i = base + t + k * 256;
        if (i < N_NODES) s += deg[i];
    }
    red[t] = s; __syncthreads();
    for (int off = 128; off > 0; off >>= 1) {
        if (t < off) red[t] += red[t + off];
        __syncthreads();
    }
    if (t == 0) chunksum[b] = red[0];
}

__global__ void k_scanchunks(const int* __restrict__ chunksum, int* __restrict__ chunkoff,
                             int* __restrict__ rowptr) {
    __shared__ int buf[128];
    int t = threadIdx.x;  // 128 threads
    int v = (t < NCHUNKS) ? chunksum[t] : 0;
    buf[t] = v; __syncthreads();
    for (int off = 1; off < 128; off <<= 1) {
        int add = (t >= off) ? buf[t - off] : 0;
        __syncthreads();
        buf[t] += add;
        __syncthreads();
    }
    if (t < NCHUNKS) chunkoff[t] = buf[t] - v;  // exclusive
    if (t == 0) rowptr[N_NODES] = N_EDGES;      // every edge has valid dst
}

__global__ void k_scanfinal(const int* __restrict__ deg, const int* __restrict__ chunkoff,
                            int* __restrict__ rowptr, int* __restrict__ fillpos) {
    __shared__ int tsum[256];
    int b = blockIdx.x, t = threadIdx.x;
    int base = b * CHUNK + t * 8;
    int v[8]; int s = 0;
    for (int k = 0; k < 8; ++k) {
        int i = base + k;
        v[k] = (i < N_NODES) ? deg[i] : 0;
        s += v[k];
    }
    tsum[t] = s; __syncthreads();
    for (int off = 1; off < 256; off <<= 1) {
        int add = (t >= off) ? tsum[t - off] : 0;
        __syncthreads();
        tsum[t] += add;
        __syncthreads();
    }
    int run = tsum[t] - s + chunkoff[b];
    for (int k = 0; k < 8; ++k) {
        int i = base + k;
        if (i < N_NODES) { rowptr[i] = run; fillpos[i] = run; run += v[k]; }
    }
}

// Ranged fill: grp = blockIdx&7 matches the round-robin block->XCD dispatch, so
// atomics to a 100KB fillpos slice stay resident in ONE XCD's L2. Round-4
// counters proved this: single-pass fill collapsed to VALUBusy 0.19% / 790 GB/s
// (cross-XCD atomic ping-pong, 540us) vs 2.9% / 1890 GB/s (300us) here. The 8x
// redundant edge reads are the price of L2-local atomics (mostly L3-absorbed).
// blk0 splits the edge range so each dispatch is ~155us (profiler visibility).
__global__ __launch_bounds__(256) void k_fill2(
    const int* __restrict__ src, const int* __restrict__ dst,
    int* __restrict__ fillpos, int* __restrict__ csr, int blk0)
{
    const int grp = blockIdx.x & 7;
    const int blk = blk0 + (blockIdx.x >> 3);   // edge slice [blk0, blk0+64)
    const int lo = grp * 25000, hi = lo + 25000;
    const int4* d4 = reinterpret_cast<const int4*>(dst) + blk * 12500;
    const int4* s4 = reinterpret_cast<const int4*>(src) + blk * 12500;
    for (int j = threadIdx.x; j < 12500; j += 256) {
        int4 d = d4[j];
        int4 s = s4[j];
        if (d.x >= lo && d.x < hi) { int p = atomicAdd(&fillpos[d.x], 1); csr[p] = s.x; }
        if (d.y >= lo && d.y < hi) { int p = atomicAdd(&fillpos[d.y], 1); csr[p] = s.y; }
        if (d.z >= lo && d.z < hi) { int p = atomicAdd(&fillpos[d.z], 1); csr[p] = s.z; }
        if (d.w >= lo && d.w < hi) { int p = atomicAdd(&fillpos[d.w], 1); csr[p] = s.w; }
    }
}

__global__ void k_bounds(const int* __restrict__ batch, int* __restrict__ gstart) {
    int g = blockIdx.x * blockDim.x + threadIdx.x;
    if (g > N_GRAPHS) return;
    if (g == N_GRAPHS) { gstart[g] = N_NODES; return; }
    int lo = 0, hi = N_NODES;
    while (lo < hi) {
        int mid = (lo + hi) >> 1;
        if (batch[mid] < g) lo = mid + 1; else hi = mid;
    }
    gstart[g] = lo;
}

// ---------------- Layer-0 pre-projection: y = x @ w1  (128 -> 32) ----------------

__global__ __launch_bounds__(256) void k_proj128(
    const float* __restrict__ x, fp w1, float* __restrict__ y,
    unsigned short* __restrict__ y16)
{
    __shared__ float w1s[DIM_IN * 32];  // 16 KiB
    for (int i = threadIdx.x; i < DIM_IN * 32; i += 256) w1s[i] = w1[i];
    __syncthreads();
    const int lane = threadIdx.x & 63;
    const int c = lane & 31;
    const int srcBase = lane & 32;
    int worker   = (blockIdx.x * blockDim.x + threadIdx.x) >> 5;
    int nworkers = (gridDim.x * blockDim.x) >> 5;
    for (int n = worker; n < N_NODES; n += nworkers) {
        const float* xr = x + (size_t)n * DIM_IN;
        float x0 = xr[c], x1 = xr[32 + c], x2 = xr[64 + c], x3 = xr[96 + c];
        float acc = 0.f;
        #pragma unroll
        for (int k = 0; k < 32; ++k) {
            acc = fmaf(__shfl(x0, srcBase | k, 64), w1s[k * 32 + c], acc);
            acc = fmaf(__shfl(x1, srcBase | k, 64), w1s[(32 + k) * 32 + c], acc);
            acc = fmaf(__shfl(x2, srcBase | k, 64), w1s[(64 + k) * 32 + c], acc);
            acc = fmaf(__shfl(x3, srcBase | k, 64), w1s[(96 + k) * 32 + c], acc);
        }
        y[(size_t)n * 32 + c] = acc;
        y16[(size_t)n * 32 + c] = f2h(acc);
    }
}

// ---------------- Gather with BN fold (dual-row 8B loads) ----------------
// s[n] = sc * (h[n] + sum_{j in N(n)} h[j]) + (deg+1) * sh   (BN affine commutes)
// 16 lanes per node. Per pair of edges: ONE uint2 load per lane — lanes sub<8
// read the even edge's row, lanes sub>=8 the odd edge's row; each lane covers
// 4 channels (4q..4q+3). UNCHANGED: awaiting first clean profile next round.

__global__ __launch_bounds__(256) void k_gather8(
    const float* __restrict__ h, const unsigned short* __restrict__ h16,
    const int* __restrict__ rowptr, const int* __restrict__ csr,
    float* __restrict__ sout,
    const float* __restrict__ stats, fp gamma, fp beta)
{
    const int lane = threadIdx.x & 63;
    const int sub  = lane & 15;      // position in 16-lane node group
    const int q    = sub & 7;        // quarter-row slot (uint2 index in row)
    const int hh   = sub >> 3;       // 0: even edges, 1: odd edges
    const int srcBase = lane & 48;   // group base within wave
    // BN affine for this lane's 4 channels c = 4q..4q+3
    float sc0 = 1.f, sc1 = 1.f, sc2 = 1.f, sc3 = 1.f;
    float sh0 = 0.f, sh1 = 0.f, sh2 = 0.f, sh3 = 0.f;
    if (stats) {
        const int c0 = 4 * q;
        float m0 = stats[c0 + 0] * (1.f / N_NODES);
        float m1 = stats[c0 + 1] * (1.f / N_NODES);
        float m2 = stats[c0 + 2] * (1.f / N_NODES);
        float m3 = stats[c0 + 3] * (1.f / N_NODES);
        float v0 = stats[32 + c0 + 0] * (1.f / N_NODES) - m0 * m0;
        float v1 = stats[32 + c0 + 1] * (1.f / N_NODES) - m1 * m1;
        float v2 = stats[32 + c0 + 2] * (1.f / N_NODES) - m2 * m2;
        float v3 = stats[32 + c0 + 3] * (1.f / N_NODES) - m3 * m3;
        sc0 = gamma[c0 + 0] * rsqrtf(v0 + BN_EPS);
        sc1 = gamma[c0 + 1] * rsqrtf(v1 + BN_EPS);
        sc2 = gamma[c0 + 2] * rsqrtf(v2 + BN_EPS);
        sc3 = gamma[c0 + 3] * rsqrtf(v3 + BN_EPS);
        sh0 = beta[c0 + 0] - m0 * sc0;
        sh1 = beta[c0 + 1] - m1 * sc1;
        sh2 = beta[c0 + 2] - m2 * sc2;
        sh3 = beta[c0 + 3] - m3 * sc3;
    }
    const uint2*  hp2 = reinterpret_cast<const uint2*>(h16);  // row = 8 uint2 (64B)
    const float4* hs4 = reinterpret_cast<const float4*>(h);   // row = 8 float4
    float4* so4 = reinterpret_cast<float4*>(sout);
    int worker   = (blockIdx.x * blockDim.x + threadIdx.x) >> 4;
    int nworkers = (gridDim.x * blockDim.x) >> 4;
    for (int n = worker; n < N_NODES; n += nworkers) {
        int e0 = rowptr[n], e1 = rowptr[n + 1];
        float a0 = 0.f, a1 = 0.f, a2 = 0.f, a3 = 0.f;
        int e = e0;
        while (e < e1) {
            int rem = e1 - e;
            int cnt = rem < 16 ? rem : 16;
            int myidx = (sub < cnt) ? csr[e + sub] : 0;
            if (cnt == 16) {
                int i0 = __shfl(myidx, srcBase | (0  + hh), 64);
                int i1 = __shfl(myidx, srcBase | (2  + hh), 64);
                int i2 = __shfl(myidx, srcBase | (4  + hh), 64);
                int i3 = __shfl(myidx, srcBase | (6  + hh), 64);
                int i4 = __shfl(myidx, srcBase | (8  + hh), 64);
                int i5 = __shfl(myidx, srcBase | (10 + hh), 64);
                int i6 = __shfl(myidx, srcBase | (12 + hh), 64);
                int i7 = __shfl(myidx, srcBase | (14 + hh), 64);
                uint2 u0 = hp2[(size_t)i0 * 8 + q];
                uint2 u1 = hp2[(size_t)i1 * 8 + q];
                uint2 u2 = hp2[(size_t)i2 * 8 + q];
                uint2 u3 = hp2[(size_t)i3 * 8 + q];
                uint2 u4 = hp2[(size_t)i4 * 8 + q];
                uint2 u5 = hp2[(size_t)i5 * 8 + q];
                uint2 u6 = hp2[(size_t)i6 * 8 + q];
                uint2 u7 = hp2[(size_t)i7 * 8 + q];
                float2 fA, fB;
                fA = h2f2(u0.x); fB = h2f2(u0.y);
                a0 += fA.x; a1 += fA.y; a2 += fB.x; a3 += fB.y;
                fA = h2f2(u1.x); fB = h2f2(u1.y);
                a0 += fA.x; a1 += fA.y; a2 += fB.x; a3 += fB.y;
                fA = h2f2(u2.x); fB = h2f2(u2.y);
                a0 += fA.x; a1 += fA.y; a2 += fB.x; a3 += fB.y;
                fA = h2f2(u3.x); fB = h2f2(u3.y);
                a0 += fA.x; a1 += fA.y; a2 += fB.x; a3 += fB.y;
                fA = h2f2(u4.x); fB = h2f2(u4.y);
                a0 += fA.x; a1 += fA.y; a2 += fB.x; a3 += fB.y;
                fA = h2f2(u5.x); fB = h2f2(u5.y);
                a0 += fA.x; a1 += fA.y; a2 += fB.x; a3 += fB.y;
                fA = h2f2(u6.x); fB = h2f2(u6.y);
                a0 += fA.x; a1 += fA.y; a2 += fB.x; a3 += fB.y;
                fA = h2f2(u7.x); fB = h2f2(u7.y);
                a0 += fA.x; a1 += fA.y; a2 += fB.x; a3 += fB.y;
            } else {
                int k = 0;
                for (; k + 2 <= cnt; k += 2) {
                    int i = __shfl(myidx, srcBase | (k + hh), 64);
                    uint2 u = hp2[(size_t)i * 8 + q];
                    float2 fA = h2f2(u.x), fB = h2f2(u.y);
                    a0 += fA.x; a1 += fA.y; a2 += fB.x; a3 += fB.y;
                }
                if (k < cnt) {  // odd tail: only half hh==0 contributes
                    int i = __shfl(myidx, srcBase | k, 64);
                    if (hh == 0) {
                        uint2 u = hp2[(size_t)i * 8 + q];
                        float2 fA = h2f2(u.x), fB = h2f2(u.y);
                        a0 += fA.x; a1 += fA.y; a2 += fB.x; a3 += fB.y;
                    }
                }
            }
            e += cnt;
        }
        // combine even/odd halves within the group
        a0 += __shfl_xor(a0, 8, 64);
        a1 += __shfl_xor(a1, 8, 64);
        a2 += __shfl_xor(a2, 8, 64);
        a3 += __shfl_xor(a3, 8, 64);
        // self + BN; write by the hh==0 half (8 lanes x 16B = full 128B row)
        float4 self = hs4[(size_t)n * 8 + q];
        float dc = (float)(e1 - e0 + 1);   // deg + 1 (self)
        float4 o;
        o.x = fmaf(a0 + self.x, sc0, dc * sh0);
        o.y = fmaf(a1 + self.y, sc1, dc * sh1);
        o.z = fmaf(a2 + self.z, sc2, dc * sh2);
        o.w = fmaf(a3 + self.w, sc3, dc * sh3);
        if (hh == 0) so4[(size_t)n * 8 + q] = o;
    }
}

// ---------------- MLP kernels (streaming, fused BN-stats) ----------------
// Write PRE-BN activation a = relu(mlp(s)) to hout (fp32) + h16out (fp16),
// accumulate per-channel sum / sum-of-squares into stats.

__global__ __launch_bounds__(256) void k_mlp32(
    const float* __restrict__ s, fp w1, fp b1, fp w2, fp b2,
    float* __restrict__ hout, unsigned short* __restrict__ h16out,
    float* __restrict__ stats)
{
    const int lane = threadIdx.x & 63;
    const int c = lane & 31;
    const int srcBase = lane & 32;
    float w1r[32], w2r[32];
    #pragma unroll
    for (int k = 0; k < 32; ++k) {
        w1r[k] = w1[k * 32 + c];
        w2r[k] = w2[k * 32 + c];
    }
    const float b1c = b1[c];
    const float b2c = b2[c];
    int worker   = (blockIdx.x * blockDim.x + threadIdx.x) >> 5;
    int nworkers = (gridDim.x * blockDim.x) >> 5;
    float s1 = 0.f, s2 = 0.f;
    for (int n = worker; n < N_NODES; n += nworkers) {
        float sv = s[(size_t)n * 32 + c];
        float acc1 = b1c;
        #pragma unroll
        for (int k = 0; k < 32; ++k)
            acc1 = fmaf(__shfl(sv, srcBase | k, 64), w1r[k], acc1);
        float h3 = fmaxf(acc1, 0.f);
        float acc2 = b2c;
        #pragma unroll
        for (int k = 0; k < 32; ++k)
            acc2 = fmaf(__shfl(h3, srcBase | k, 64), w2r[k], acc2);
        float a = fmaxf(acc2, 0.f);
        hout[(size_t)n * 32 + c] = a;
        h16out[(size_t)n * 32 + c] = f2h(a);
        s1 += a; s2 += a * a;
    }
    s1 += __shfl_xor(s1, 32, 64);
    s2 += __shfl_xor(s2, 32, 64);
    __shared__ float ls1[4][32], ls2[4][32];
    int w = threadIdx.x >> 6;
    if ((threadIdx.x & 32) == 0) { ls1[w][c] = s1; ls2[w][c] = s2; }
    __syncthreads();
    if (threadIdx.x < 32) {
        float t1 = ls1[0][c] + ls1[1][c] + ls1[2][c] + ls1[3][c];
        float t2 = ls2[0][c] + ls2[1][c] + ls2[2][c] + ls2[3][c];
        atomicAdd(&stats[c], t1);
        atomicAdd(&stats[32 + c], t2);
    }
}

// layer-0 variant: s already = (x+agg)@w1, so stage 1 is elementwise.
__global__ __launch_bounds__(256) void k_mlp0(
    const float* __restrict__ s, fp b1, fp w2, fp b2,
    float* __restrict__ hout, unsigned short* __restrict__ h16out,
    float* __restrict__ stats)
{
    const int lane = threadIdx.x & 63;
    const int c = lane & 31;
    const int srcBase = lane & 32;
    float w2r[32];
    #pragma unroll
    for (int k = 0; k < 32; ++k) w2r[k] = w2[k * 32 + c];
    const float b1c = b1[c];
    const float b2c = b2[c];
    int worker   = (blockIdx.x * blockDim.x + threadIdx.x) >> 5;
    int nworkers = (gridDim.x * blockDim.x) >> 5;
    float s1 = 0.f, s2 = 0.f;
    for (int n = worker; n < N_NODES; n += nworkers) {
        float sv = s[(size_t)n * 32 + c];
        float h3 = fmaxf(sv + b1c, 0.f);
        float acc2 = b2c;
        #pragma unroll
        for (int k = 0; k < 32; ++k)
            acc2 = fmaf(__shfl(h3, srcBase | k, 64), w2r[k], acc2);
        float a = fmaxf(acc2, 0.f);
        hout[(size_t)n * 32 + c] = a;
        h16out[(size_t)n * 32 + c] = f2h(a);
        s1 += a; s2 += a * a;
    }
    s1 += __shfl_xor(s1, 32, 64);
    s2 += __shfl_xor(s2, 32, 64);
    __shared__ float ls1[4][32], ls2[4][32];
    int w = threadIdx.x >> 6;
    if ((threadIdx.x & 32) == 0) { ls1[w][c] = s1; ls2[w][c] = s2; }
    __syncthreads();
    if (threadIdx.x < 32) {
        float t1 = ls1[0][c] + ls1[1][c] + ls1[2][c] + ls1[3][c];
        float t2 = ls2[0][c] + ls2[1][c] + ls2[2][c] + ls2[3][c];
        atomicAdd(&stats[c], t1);
        atomicAdd(&stats[32 + c], t2);
    }
}

// decoder last: out = relu(relu(s@w1+b1)@w2_last+b2_last), 32 -> 32 -> 128.
__global__ __launch_bounds__(256) void k_mlp_last(
    const float* __restrict__ s, fp w1, fp b1, fp w2 /*[32][128]*/, fp b2,
    float* __restrict__ out)
{
    const int lane = threadIdx.x & 63;
    const int c = lane & 31;
    float w1r[32], w2a[32], w2b[32];
    #pragma unroll
    for (int k = 0; k < 32; ++k) {
        w1r[k] = w1[k * 32 + c];
        w2a[k] = w2[k * 128 + 2 * lane];
        w2b[k] = w2[k * 128 + 2 * lane + 1];
    }
    const float b1c = b1[c];
    const float b2a = b2[2 * lane];
    const float b2b = b2[2 * lane + 1];
    int worker   = (blockIdx.x * blockDim.x + threadIdx.x) >> 6;
    int nworkers = (gridDim.x * blockDim.x) >> 6;
    for (int n = worker; n < N_NODES; n += nworkers) {
        float sv = s[(size_t)n * 32 + c];  // duplicated across halves
        float acc1 = b1c;
        #pragma unroll
        for (int k = 0; k < 32; ++k)
            acc1 = fmaf(__shfl(sv, k, 64), w1r[k], acc1);
        float h3 = fmaxf(acc1, 0.f);
        float oa = b2a, ob = b2b;
        #pragma unroll
        for (int k = 0; k < 32; ++k) {
            float v = __shfl(h3, (lane & 32) | k, 64);
            oa = fmaf(v, w2a[k], oa);
            ob = fmaf(v, w2b[k], ob);
        }
        oa = fmaxf(oa, 0.f); ob = fmaxf(ob, 0.f);
        float2 pr; pr.x = oa; pr.y = ob;
        reinterpret_cast<float2*>(out)[(size_t)n * 64 + lane] = pr;
    }
}

// Materialize post-BN encoder output once: out = sc*h + sh.
__global__ void k_bnout(const float* __restrict__ h, const float* __restrict__ stats,
                        fp gamma, fp beta, float* __restrict__ out)
{
    const int c = threadIdx.x & 31;
    float m  = stats[c] * (1.f / N_NODES);
    float vv = stats[32 + c] * (1.f / N_NODES) - m * m;
    float sc = gamma[c] * rsqrtf(vv + BN_EPS);
    float sh = beta[c] - m * sc;
    int i = blockIdx.x * blockDim.x + threadIdx.x;
    int stride = gridDim.x * blockDim.x;  // multiple of 32 -> (i&31)==c always
    for (; i < N_NODES * 32; i += stride) out[i] = fmaf(h[i], sc, sh);
}

// Global add-pool of one encoder layer into d_out global_rep slice (batch sorted).
// h holds PRE-BN values; pool of bn(h) = sc * sum(h) + cnt * sh.
__global__ void k_pool(const float* __restrict__ h, const int* __restrict__ gstart,
                       float* __restrict__ out, int col0,
                       const float* __restrict__ stats, fp gamma, fp beta)
{
    int g = blockIdx.x;
    int t = threadIdx.x;
    int f = t & 31, j = t >> 5;  // 8 node-groups x 32 features
    int n0 = gstart[g], n1 = gstart[g + 1];
    float s = 0.f;
    for (int n = n0 + j; n < n1; n += 8) s += h[(size_t)n * 32 + f];
    __shared__ float red[8][32];
    red[j][f] = s; __syncthreads();
    if (t < 32) {
        float tot = 0.f;
        #pragma unroll
        for (int k = 0; k < 8; ++k) tot += red[k][f];
        float m  = stats[f] * (1.f / N_NODES);
        float vv = stats[32 + f] * (1.f / N_NODES) - m * m;
        float sc = gamma[f] * rsqrtf(vv + BN_EPS);
        float sh = beta[f] - m * sc;
        out[g * (5 * HID) + col0 + f] = fmaf(tot, sc, (float)(n1 - n0) * sh);
    }
}

// ---------------- launch ----------------

extern "C" void kernel_launch(void* const* d_in, const int* in_sizes, int n_in,
                              void* d_out, int out_size, void* d_ws, size_t ws_size,
                              hipStream_t stream) {
    fp         x        = (fp)d_in[0];
    const int* edge     = (const int*)d_in[1];
    const int* batch    = (const int*)d_in[2];
    fp e0_w1 = (fp)d_in[3],  e0_b1 = (fp)d_in[4];
    fp e0_w2 = (fp)d_in[5],  e0_b2 = (fp)d_in[6];
    fp enc_w1 = (fp)d_in[7],  enc_b1 = (fp)d_in[8];
    fp enc_w2 = (fp)d_in[9],  enc_b2 = (fp)d_in[10];
    fp enc_gamma = (fp)d_in[11], enc_beta = (fp)d_in[12];
    fp dec_w1 = (fp)d_in[13], dec_b1 = (fp)d_in[14];
    fp dec_w2 = (fp)d_in[15], dec_b2 = (fp)d_in[16];
    fp dec_w2_last = (fp)d_in[17], dec_b2_last = (fp)d_in[18];
    fp dec_gamma = (fp)d_in[19], dec_beta = (fp)d_in[20];

    const int* srcp = edge;            // edge_index[0]
    const int* dstp = edge + N_EDGES;  // edge_index[1]

    float* out_enc    = (float*)d_out;                            // [200000*32]
    float* out_dec    = (float*)d_out + (size_t)N_NODES * 32;     // [200000*128]
    float* out_global = (float*)d_out + (size_t)N_NODES * 160;    // [512*160]

    // workspace carve (256B aligned)
    char* p = (char*)d_ws;
    auto alloc = [&](size_t bytes) -> void* {
        void* r = (void*)p;
        p += (bytes + 255) & ~(size_t)255;
        return r;
    };
    int*   rowptr   = (int*)alloc((N_NODES + 1) * sizeof(int));
    int*   fillpos  = (int*)alloc(N_NODES * sizeof(int));
    int*   deg      = (int*)alloc(N_NODES * sizeof(int));
    int*   chunksum = (int*)alloc(128 * sizeof(int));
    int*   chunkoff = (int*)alloc(128 * sizeof(int));
    int*   gstart   = (int*)alloc((N_GRAPHS + 1) * sizeof(int));
    float* stats    = (float*)alloc(9 * 64 * sizeof(float));
    int*   csr      = (int*)alloc((size_t)N_EDGES * sizeof(int));
    float* hbuf     = (float*)alloc((size_t)N_NODES * 32 * sizeof(float));
    float* sbuf     = (float*)alloc((size_t)N_NODES * 32 * sizeof(float));
    unsigned short* h16 = (unsigned short*)alloc((size_t)N_NODES * 32 * sizeof(unsigned short));

    hipMemsetAsync(deg, 0, N_NODES * sizeof(int), stream);
    hipMemsetAsync(stats, 0, 9 * 64 * sizeof(float), stream);

    // CSR build (fill split into 2 half-dispatches for profiler visibility)
    k_hist2<<<512, 256, 0, stream>>>(dstp, deg);
    k_chunksum<<<NCHUNKS, 256, 0, stream>>>(deg, chunksum);
    k_scanchunks<<<1, 128, 0, stream>>>(chunksum, chunkoff, rowptr);
    k_scanfinal<<<NCHUNKS, 256, 0, stream>>>(deg, chunkoff, rowptr, fillpos);
    k_fill2<<<512, 256, 0, stream>>>(srcp, dstp, fillpos, csr, 0);
    k_fill2<<<512, 256, 0, stream>>>(srcp, dstp, fillpos, csr, 64);
    k_bounds<<<3, 256, 0, stream>>>(batch, gstart);

    // ---- Encoder layer 0 (pre-projected; no BN on gather input) ----
    k_proj128<<<1024, 256, 0, stream>>>(x, e0_w1, hbuf, h16);   // hbuf/h16 = y = x@w1
    k_gather8<<<2048, 256, 0, stream>>>(hbuf, h16, rowptr, csr, sbuf,
                                        nullptr, nullptr, nullptr);
    k_mlp0<<<1024, 256, 0, stream>>>(sbuf, e0_b1, e0_w2, e0_b2, hbuf, h16, stats);
    k_pool<<<N_GRAPHS, 256, 0, stream>>>(hbuf, gstart, out_global, 0,
                                         stats, enc_gamma, enc_beta);

    // ---- Encoder layers 1..4 (32 -> 32); gather applies prev layer's BN ----
    for (int i = 0; i < 4; ++i) {
        float* st_prev = stats + i * 64;          // BN stats of h currently in hbuf
        float* st      = stats + (1 + i) * 64;
        k_gather8<<<2048, 256, 0, stream>>>(hbuf, h16, rowptr, csr, sbuf,
                                            st_prev, enc_gamma + i * 32, enc_beta + i * 32);
        k_mlp32<<<1024, 256, 0, stream>>>(sbuf,
                                          enc_w1 + i * 1024, enc_b1 + i * 32,
                                          enc_w2 + i * 1024, enc_b2 + i * 32,
                                          hbuf, h16, st);
        k_pool<<<N_GRAPHS, 256, 0, stream>>>(hbuf, gstart, out_global, (1 + i) * 32,
                                             st, enc_gamma + (1 + i) * 32,
                                             enc_beta + (1 + i) * 32);
    }

    // encoded_rep = bn(enc layer 4 output)
    k_bnout<<<2048, 256, 0, stream>>>(hbuf, stats + 4 * 64,
                                      enc_gamma + 4 * 32, enc_beta + 4 * 32, out_enc);

    // ---- Decoder layers 0..3 (32 -> 32, BN) ----
    for (int i = 0; i < 4; ++i) {
        float* st_prev = (i == 0) ? (stats + 4 * 64) : (stats + (4 + i) * 64);
        fp g_prev      = (i == 0) ? (enc_gamma + 4 * 32) : (dec_gamma + (i - 1) * 32);
        fp b_prev      = (i == 0) ? (enc_beta  + 4 * 32) : (dec_beta  + (i - 1) * 32);
        float* st      = stats + (5 + i) * 64;
        k_gather8<<<2048, 256, 0, stream>>>(hbuf, h16, rowptr, csr, sbuf,
                                            st_prev, g_prev, b_prev);
        k_mlp32<<<1024, 256, 0, stream>>>(sbuf,
                                          dec_w1 + i * 1024, dec_b1 + i * 32,
                                          dec_w2 + i * 1024, dec_b2 + i * 32,
                                          hbuf, h16, st);
    }

    // ---- Decoder layer 4 (32 -> 32 -> 128, relu, no BN) ----
    k_gather8<<<2048, 256, 0, stream>>>(hbuf, h16, rowptr, csr, sbuf,
                                        stats + 8 * 64, dec_gamma + 3 * 32,
                                        dec_beta + 3 * 32);
    k_mlp_last<<<1024, 256, 0, stream>>>(sbuf,
                                         dec_w1 + 4 * 1024, dec_b1 + 4 * 32,
                                         dec_w2_last, dec_b2_last, out_dec);
}

// Round 9
// 2754.295 us; speedup vs baseline: 1.1160x; 1.0187x over previous
//
#include <hip/hip_runtime.h>
#include <hip/hip_bf16.h>
#include <hip/hip_fp16.h>
#include <string.h>

#define N_NODES  200000
#define N_EDGES  6400000
#define N_GRAPHS 512
#define DIM_IN   128
#define HID      32
#define BN_EPS   1e-5f

// chunked scan params
#define CHUNK    2048
#define NCHUNKS  98   // ceil(200000/2048)

typedef const float* fp;

// fp16 storage helpers (RNE via v_cvt_f16_f32 / v_cvt_f32_f16)
__device__ __forceinline__ unsigned short f2h(float f) {
    __half h = __float2half(f);
    unsigned short u; __builtin_memcpy(&u, &h, 2); return u;
}
__device__ __forceinline__ float2 h2f2(unsigned int u) {
    __half2 h; __builtin_memcpy(&h, &u, 4);
    return __half22float2(h);
}

// ---------------- CSR build ----------------

// LDS-binned histogram: 16 node-ranges of 12500 (50KB LDS each), 32 blocks/range.
// Round-6 counters: grid=256 capped occupancy at 1 block/CU (11.7%), VALUBusy
// 4.6%, 527 GB/s -> latency-bound. Round-8 verified the fix (grid 512 + 4-way
// ILP): hist2 fell out of top-5 (220 -> <190us), total -147us.
__global__ __launch_bounds__(256) void k_hist2(const int* __restrict__ dst,
                                               int* __restrict__ deg) {
    __shared__ int lh[12500];  // 50 KB
    const int grp = blockIdx.x & 15;        // node range [0,16)
    const int blk = blockIdx.x >> 4;        // edge slice [0,32)
    const int lo = grp * 12500;
    for (int j = threadIdx.x; j < 12500; j += 256) lh[j] = 0;
    __syncthreads();
    // slice = 50000 int4 = 200K edges, processed as 4 sub-segments of 12500 int4
    const int4* d4 = reinterpret_cast<const int4*>(dst) + blk * 50000;
    for (int j = threadIdx.x; j < 12500; j += 256) {
        int4 v0 = d4[j];
        int4 v1 = d4[j + 12500];
        int4 v2 = d4[j + 25000];
        int4 v3 = d4[j + 37500];
        int a;
        a = v0.x - lo; if ((unsigned)a < 12500u) atomicAdd(&lh[a], 1);
        a = v0.y - lo; if ((unsigned)a < 12500u) atomicAdd(&lh[a], 1);
        a = v0.z - lo; if ((unsigned)a < 12500u) atomicAdd(&lh[a], 1);
        a = v0.w - lo; if ((unsigned)a < 12500u) atomicAdd(&lh[a], 1);
        a = v1.x - lo; if ((unsigned)a < 12500u) atomicAdd(&lh[a], 1);
        a = v1.y - lo; if ((unsigned)a < 12500u) atomicAdd(&lh[a], 1);
        a = v1.z - lo; if ((unsigned)a < 12500u) atomicAdd(&lh[a], 1);
        a = v1.w - lo; if ((unsigned)a < 12500u) atomicAdd(&lh[a], 1);
        a = v2.x - lo; if ((unsigned)a < 12500u) atomicAdd(&lh[a], 1);
        a = v2.y - lo; if ((unsigned)a < 12500u) atomicAdd(&lh[a], 1);
        a = v2.z - lo; if ((unsigned)a < 12500u) atomicAdd(&lh[a], 1);
        a = v2.w - lo; if ((unsigned)a < 12500u) atomicAdd(&lh[a], 1);
        a = v3.x - lo; if ((unsigned)a < 12500u) atomicAdd(&lh[a], 1);
        a = v3.y - lo; if ((unsigned)a < 12500u) atomicAdd(&lh[a], 1);
        a = v3.z - lo; if ((unsigned)a < 12500u) atomicAdd(&lh[a], 1);
        a = v3.w - lo; if ((unsigned)a < 12500u) atomicAdd(&lh[a], 1);
    }
    __syncthreads();
    for (int j = threadIdx.x; j < 12500; j += 256) {
        int c = lh[j];
        if (c) atomicAdd(&deg[lo + j], c);
    }
}

__global__ void k_chunksum(const int* __restrict__ deg, int* __restrict__ chunksum) {
    __shared__ int red[256];
    int b = blockIdx.x, t = threadIdx.x;
    int base = b * CHUNK;
    int s = 0;
    for (int k = 0; k < 8; ++k) {
        int i = base + t + k * 256;
        if (i < N_NODES) s += deg[i];
    }
    red[t] = s; __syncthreads();
    for (int off = 128; off > 0; off >>= 1) {
        if (t < off) red[t] += red[t + off];
        __syncthreads();
    }
    if (t == 0) chunksum[b] = red[0];
}

__global__ void k_scanchunks(const int* __restrict__ chunksum, int* __restrict__ chunkoff,
                             int* __restrict__ rowptr) {
    __shared__ int buf[128];
    int t = threadIdx.x;  // 128 threads
    int v = (t < NCHUNKS) ? chunksum[t] : 0;
    buf[t] = v; __syncthreads();
    for (int off = 1; off < 128; off <<= 1) {
        int add = (t >= off) ? buf[t - off] : 0;
        __syncthreads();
        buf[t] += add;
        __syncthreads();
    }
    if (t < NCHUNKS) chunkoff[t] = buf[t] - v;  // exclusive
    if (t == 0) rowptr[N_NODES] = N_EDGES;      // every edge has valid dst
}

__global__ void k_scanfinal(const int* __restrict__ deg, const int* __restrict__ chunkoff,
                            int* __restrict__ rowptr, int* __restrict__ fillpos) {
    __shared__ int tsum[256];
    int b = blockIdx.x, t = threadIdx.x;
    int base = b * CHUNK + t * 8;
    int v[8]; int s = 0;
    for (int k = 0; k < 8; ++k) {
        int i = base + k;
        v[k] = (i < N_NODES) ? deg[i] : 0;
        s += v[k];
    }
    tsum[t] = s; __syncthreads();
    for (int off = 1; off < 256; off <<= 1) {
        int add = (t >= off) ? tsum[t - off] : 0;
        __syncthreads();
        tsum[t] += add;
        __syncthreads();
    }
    int run = tsum[t] - s + chunkoff[b];
    for (int k = 0; k < 8; ++k) {
        int i = base + k;
        if (i < N_NODES) { rowptr[i] = run; fillpos[i] = run; run += v[k]; }
    }
}

// Ranged fill: grp = blockIdx&7 matches the round-robin block->XCD dispatch, so
// atomics to a 100KB fillpos slice stay resident in ONE XCD's L2 (round-4
// counters: single-pass fill = cross-XCD ping-pong, 540us vs 300us).
// Round-8 counters establish the occupancy->BW curve: 2 blocks/CU -> 1515 GB/s,
// 4 blocks/CU -> 1890 GB/s, VALUBusy ~2.3% (concurrency-limited, not atomic-
// limited). This round: 3125 int4/block, 2048 blocks/dispatch = 8 blocks/CU
// (32 waves, full occupancy) for maximum in-flight loads.
__global__ __launch_bounds__(256) void k_fill2(
    const int* __restrict__ src, const int* __restrict__ dst,
    int* __restrict__ fillpos, int* __restrict__ csr, int blk0)
{
    const int grp = blockIdx.x & 7;
    const int blk = blk0 + (blockIdx.x >> 3);   // 3125-int4 slice index [0,512)
    const int lo = grp * 25000, hi = lo + 25000;
    const int4* d4 = reinterpret_cast<const int4*>(dst) + blk * 3125;
    const int4* s4 = reinterpret_cast<const int4*>(src) + blk * 3125;
    for (int j = threadIdx.x; j < 3125; j += 256) {
        int4 d = d4[j];
        int4 s = s4[j];
        if (d.x >= lo && d.x < hi) { int p = atomicAdd(&fillpos[d.x], 1); csr[p] = s.x; }
        if (d.y >= lo && d.y < hi) { int p = atomicAdd(&fillpos[d.y], 1); csr[p] = s.y; }
        if (d.z >= lo && d.z < hi) { int p = atomicAdd(&fillpos[d.z], 1); csr[p] = s.z; }
        if (d.w >= lo && d.w < hi) { int p = atomicAdd(&fillpos[d.w], 1); csr[p] = s.w; }
    }
}

__global__ void k_bounds(const int* __restrict__ batch, int* __restrict__ gstart) {
    int g = blockIdx.x * blockDim.x + threadIdx.x;
    if (g > N_GRAPHS) return;
    if (g == N_GRAPHS) { gstart[g] = N_NODES; return; }
    int lo = 0, hi = N_NODES;
    while (lo < hi) {
        int mid = (lo + hi) >> 1;
        if (batch[mid] < g) lo = mid + 1; else hi = mid;
    }
    gstart[g] = lo;
}

// ---------------- Layer-0 pre-projection: y = x @ w1  (128 -> 32) ----------------

__global__ __launch_bounds__(256) void k_proj128(
    const float* __restrict__ x, fp w1, float* __restrict__ y,
    unsigned short* __restrict__ y16)
{
    __shared__ float w1s[DIM_IN * 32];  // 16 KiB
    for (int i = threadIdx.x; i < DIM_IN * 32; i += 256) w1s[i] = w1[i];
    __syncthreads();
    const int lane = threadIdx.x & 63;
    const int c = lane & 31;
    const int srcBase = lane & 32;
    int worker   = (blockIdx.x * blockDim.x + threadIdx.x) >> 5;
    int nworkers = (gridDim.x * blockDim.x) >> 5;
    for (int n = worker; n < N_NODES; n += nworkers) {
        const float* xr = x + (size_t)n * DIM_IN;
        float x0 = xr[c], x1 = xr[32 + c], x2 = xr[64 + c], x3 = xr[96 + c];
        float acc = 0.f;
        #pragma unroll
        for (int k = 0; k < 32; ++k) {
            acc = fmaf(__shfl(x0, srcBase | k, 64), w1s[k * 32 + c], acc);
            acc = fmaf(__shfl(x1, srcBase | k, 64), w1s[(32 + k) * 32 + c], acc);
            acc = fmaf(__shfl(x2, srcBase | k, 64), w1s[(64 + k) * 32 + c], acc);
            acc = fmaf(__shfl(x3, srcBase | k, 64), w1s[(96 + k) * 32 + c], acc);
        }
        y[(size_t)n * 32 + c] = acc;
        y16[(size_t)n * 32 + c] = f2h(acc);
    }
}

// ---------------- Gather with BN fold (dual-row 8B loads) ----------------
// s[n] = sc * (h[n] + sum_{j in N(n)} h[j]) + (deg+1) * sh   (BN affine commutes)
// 16 lanes per node. Per pair of edges: ONE uint2 load per lane — lanes sub<8
// read the even edge's row, lanes sub>=8 the odd edge's row; each lane covers
// 4 channels (4q..4q+3). UNCHANGED: awaiting first clean profile next round.

__global__ __launch_bounds__(256) void k_gather8(
    const float* __restrict__ h, const unsigned short* __restrict__ h16,
    const int* __restrict__ rowptr, const int* __restrict__ csr,
    float* __restrict__ sout,
    const float* __restrict__ stats, fp gamma, fp beta)
{
    const int lane = threadIdx.x & 63;
    const int sub  = lane & 15;      // position in 16-lane node group
    const int q    = sub & 7;        // quarter-row slot (uint2 index in row)
    const int hh   = sub >> 3;       // 0: even edges, 1: odd edges
    const int srcBase = lane & 48;   // group base within wave
    // BN affine for this lane's 4 channels c = 4q..4q+3
    float sc0 = 1.f, sc1 = 1.f, sc2 = 1.f, sc3 = 1.f;
    float sh0 = 0.f, sh1 = 0.f, sh2 = 0.f, sh3 = 0.f;
    if (stats) {
        const int c0 = 4 * q;
        float m0 = stats[c0 + 0] * (1.f / N_NODES);
        float m1 = stats[c0 + 1] * (1.f / N_NODES);
        float m2 = stats[c0 + 2] * (1.f / N_NODES);
        float m3 = stats[c0 + 3] * (1.f / N_NODES);
        float v0 = stats[32 + c0 + 0] * (1.f / N_NODES) - m0 * m0;
        float v1 = stats[32 + c0 + 1] * (1.f / N_NODES) - m1 * m1;
        float v2 = stats[32 + c0 + 2] * (1.f / N_NODES) - m2 * m2;
        float v3 = stats[32 + c0 + 3] * (1.f / N_NODES) - m3 * m3;
        sc0 = gamma[c0 + 0] * rsqrtf(v0 + BN_EPS);
        sc1 = gamma[c0 + 1] * rsqrtf(v1 + BN_EPS);
        sc2 = gamma[c0 + 2] * rsqrtf(v2 + BN_EPS);
        sc3 = gamma[c0 + 3] * rsqrtf(v3 + BN_EPS);
        sh0 = beta[c0 + 0] - m0 * sc0;
        sh1 = beta[c0 + 1] - m1 * sc1;
        sh2 = beta[c0 + 2] - m2 * sc2;
        sh3 = beta[c0 + 3] - m3 * sc3;
    }
    const uint2*  hp2 = reinterpret_cast<const uint2*>(h16);  // row = 8 uint2 (64B)
    const float4* hs4 = reinterpret_cast<const float4*>(h);   // row = 8 float4
    float4* so4 = reinterpret_cast<float4*>(sout);
    int worker   = (blockIdx.x * blockDim.x + threadIdx.x) >> 4;
    int nworkers = (gridDim.x * blockDim.x) >> 4;
    for (int n = worker; n < N_NODES; n += nworkers) {
        int e0 = rowptr[n], e1 = rowptr[n + 1];
        float a0 = 0.f, a1 = 0.f, a2 = 0.f, a3 = 0.f;
        int e = e0;
        while (e < e1) {
            int rem = e1 - e;
            int cnt = rem < 16 ? rem : 16;
            int myidx = (sub < cnt) ? csr[e + sub] : 0;
            if (cnt == 16) {
                int i0 = __shfl(myidx, srcBase | (0  + hh), 64);
                int i1 = __shfl(myidx, srcBase | (2  + hh), 64);
                int i2 = __shfl(myidx, srcBase | (4  + hh), 64);
                int i3 = __shfl(myidx, srcBase | (6  + hh), 64);
                int i4 = __shfl(myidx, srcBase | (8  + hh), 64);
                int i5 = __shfl(myidx, srcBase | (10 + hh), 64);
                int i6 = __shfl(myidx, srcBase | (12 + hh), 64);
                int i7 = __shfl(myidx, srcBase | (14 + hh), 64);
                uint2 u0 = hp2[(size_t)i0 * 8 + q];
                uint2 u1 = hp2[(size_t)i1 * 8 + q];
                uint2 u2 = hp2[(size_t)i2 * 8 + q];
                uint2 u3 = hp2[(size_t)i3 * 8 + q];
                uint2 u4 = hp2[(size_t)i4 * 8 + q];
                uint2 u5 = hp2[(size_t)i5 * 8 + q];
                uint2 u6 = hp2[(size_t)i6 * 8 + q];
                uint2 u7 = hp2[(size_t)i7 * 8 + q];
                float2 fA, fB;
                fA = h2f2(u0.x); fB = h2f2(u0.y);
                a0 += fA.x; a1 += fA.y; a2 += fB.x; a3 += fB.y;
                fA = h2f2(u1.x); fB = h2f2(u1.y);
                a0 += fA.x; a1 += fA.y; a2 += fB.x; a3 += fB.y;
                fA = h2f2(u2.x); fB = h2f2(u2.y);
                a0 += fA.x; a1 += fA.y; a2 += fB.x; a3 += fB.y;
                fA = h2f2(u3.x); fB = h2f2(u3.y);
                a0 += fA.x; a1 += fA.y; a2 += fB.x; a3 += fB.y;
                fA = h2f2(u4.x); fB = h2f2(u4.y);
                a0 += fA.x; a1 += fA.y; a2 += fB.x; a3 += fB.y;
                fA = h2f2(u5.x); fB = h2f2(u5.y);
                a0 += fA.x; a1 += fA.y; a2 += fB.x; a3 += fB.y;
                fA = h2f2(u6.x); fB = h2f2(u6.y);
                a0 += fA.x; a1 += fA.y; a2 += fB.x; a3 += fB.y;
                fA = h2f2(u7.x); fB = h2f2(u7.y);
                a0 += fA.x; a1 += fA.y; a2 += fB.x; a3 += fB.y;
            } else {
                int k = 0;
                for (; k + 2 <= cnt; k += 2) {
                    int i = __shfl(myidx, srcBase | (k + hh), 64);
                    uint2 u = hp2[(size_t)i * 8 + q];
                    float2 fA = h2f2(u.x), fB = h2f2(u.y);
                    a0 += fA.x; a1 += fA.y; a2 += fB.x; a3 += fB.y;
                }
                if (k < cnt) {  // odd tail: only half hh==0 contributes
                    int i = __shfl(myidx, srcBase | k, 64);
                    if (hh == 0) {
                        uint2 u = hp2[(size_t)i * 8 + q];
                        float2 fA = h2f2(u.x), fB = h2f2(u.y);
                        a0 += fA.x; a1 += fA.y; a2 += fB.x; a3 += fB.y;
                    }
                }
            }
            e += cnt;
        }
        // combine even/odd halves within the group
        a0 += __shfl_xor(a0, 8, 64);
        a1 += __shfl_xor(a1, 8, 64);
        a2 += __shfl_xor(a2, 8, 64);
        a3 += __shfl_xor(a3, 8, 64);
        // self + BN; write by the hh==0 half (8 lanes x 16B = full 128B row)
        float4 self = hs4[(size_t)n * 8 + q];
        float dc = (float)(e1 - e0 + 1);   // deg + 1 (self)
        float4 o;
        o.x = fmaf(a0 + self.x, sc0, dc * sh0);
        o.y = fmaf(a1 + self.y, sc1, dc * sh1);
        o.z = fmaf(a2 + self.z, sc2, dc * sh2);
        o.w = fmaf(a3 + self.w, sc3, dc * sh3);
        if (hh == 0) so4[(size_t)n * 8 + q] = o;
    }
}

// ---------------- MLP kernels (streaming, fused BN-stats) ----------------
// Write PRE-BN activation a = relu(mlp(s)) to hout (fp32) + h16out (fp16),
// accumulate per-channel sum / sum-of-squares into stats.

__global__ __launch_bounds__(256) void k_mlp32(
    const float* __restrict__ s, fp w1, fp b1, fp w2, fp b2,
    float* __restrict__ hout, unsigned short* __restrict__ h16out,
    float* __restrict__ stats)
{
    const int lane = threadIdx.x & 63;
    const int c = lane & 31;
    const int srcBase = lane & 32;
    float w1r[32], w2r[32];
    #pragma unroll
    for (int k = 0; k < 32; ++k) {
        w1r[k] = w1[k * 32 + c];
        w2r[k] = w2[k * 32 + c];
    }
    const float b1c = b1[c];
    const float b2c = b2[c];
    int worker   = (blockIdx.x * blockDim.x + threadIdx.x) >> 5;
    int nworkers = (gridDim.x * blockDim.x) >> 5;
    float s1 = 0.f, s2 = 0.f;
    for (int n = worker; n < N_NODES; n += nworkers) {
        float sv = s[(size_t)n * 32 + c];
        float acc1 = b1c;
        #pragma unroll
        for (int k = 0; k < 32; ++k)
            acc1 = fmaf(__shfl(sv, srcBase | k, 64), w1r[k], acc1);
        float h3 = fmaxf(acc1, 0.f);
        float acc2 = b2c;
        #pragma unroll
        for (int k = 0; k < 32; ++k)
            acc2 = fmaf(__shfl(h3, srcBase | k, 64), w2r[k], acc2);
        float a = fmaxf(acc2, 0.f);
        hout[(size_t)n * 32 + c] = a;
        h16out[(size_t)n * 32 + c] = f2h(a);
        s1 += a; s2 += a * a;
    }
    s1 += __shfl_xor(s1, 32, 64);
    s2 += __shfl_xor(s2, 32, 64);
    __shared__ float ls1[4][32], ls2[4][32];
    int w = threadIdx.x >> 6;
    if ((threadIdx.x & 32) == 0) { ls1[w][c] = s1; ls2[w][c] = s2; }
    __syncthreads();
    if (threadIdx.x < 32) {
        float t1 = ls1[0][c] + ls1[1][c] + ls1[2][c] + ls1[3][c];
        float t2 = ls2[0][c] + ls2[1][c] + ls2[2][c] + ls2[3][c];
        atomicAdd(&stats[c], t1);
        atomicAdd(&stats[32 + c], t2);
    }
}

// layer-0 variant: s already = (x+agg)@w1, so stage 1 is elementwise.
__global__ __launch_bounds__(256) void k_mlp0(
    const float* __restrict__ s, fp b1, fp w2, fp b2,
    float* __restrict__ hout, unsigned short* __restrict__ h16out,
    float* __restrict__ stats)
{
    const int lane = threadIdx.x & 63;
    const int c = lane & 31;
    const int srcBase = lane & 32;
    float w2r[32];
    #pragma unroll
    for (int k = 0; k < 32; ++k) w2r[k] = w2[k * 32 + c];
    const float b1c = b1[c];
    const float b2c = b2[c];
    int worker   = (blockIdx.x * blockDim.x + threadIdx.x) >> 5;
    int nworkers = (gridDim.x * blockDim.x) >> 5;
    float s1 = 0.f, s2 = 0.f;
    for (int n = worker; n < N_NODES; n += nworkers) {
        float sv = s[(size_t)n * 32 + c];
        float h3 = fmaxf(sv + b1c, 0.f);
        float acc2 = b2c;
        #pragma unroll
        for (int k = 0; k < 32; ++k)
            acc2 = fmaf(__shfl(h3, srcBase | k, 64), w2r[k], acc2);
        float a = fmaxf(acc2, 0.f);
        hout[(size_t)n * 32 + c] = a;
        h16out[(size_t)n * 32 + c] = f2h(a);
        s1 += a; s2 += a * a;
    }
    s1 += __shfl_xor(s1, 32, 64);
    s2 += __shfl_xor(s2, 32, 64);
    __shared__ float ls1[4][32], ls2[4][32];
    int w = threadIdx.x >> 6;
    if ((threadIdx.x & 32) == 0) { ls1[w][c] = s1; ls2[w][c] = s2; }
    __syncthreads();
    if (threadIdx.x < 32) {
        float t1 = ls1[0][c] + ls1[1][c] + ls1[2][c] + ls1[3][c];
        float t2 = ls2[0][c] + ls2[1][c] + ls2[2][c] + ls2[3][c];
        atomicAdd(&stats[c], t1);
        atomicAdd(&stats[32 + c], t2);
    }
}

// decoder last: out = relu(relu(s@w1+b1)@w2_last+b2_last), 32 -> 32 -> 128.
__global__ __launch_bounds__(256) void k_mlp_last(
    const float* __restrict__ s, fp w1, fp b1, fp w2 /*[32][128]*/, fp b2,
    float* __restrict__ out)
{
    const int lane = threadIdx.x & 63;
    const int c = lane & 31;
    float w1r[32], w2a[32], w2b[32];
    #pragma unroll
    for (int k = 0; k < 32; ++k) {
        w1r[k] = w1[k * 32 + c];
        w2a[k] = w2[k * 128 + 2 * lane];
        w2b[k] = w2[k * 128 + 2 * lane + 1];
    }
    const float b1c = b1[c];
    const float b2a = b2[2 * lane];
    const float b2b = b2[2 * lane + 1];
    int worker   = (blockIdx.x * blockDim.x + threadIdx.x) >> 6;
    int nworkers = (gridDim.x * blockDim.x) >> 6;
    for (int n = worker; n < N_NODES; n += nworkers) {
        float sv = s[(size_t)n * 32 + c];  // duplicated across halves
        float acc1 = b1c;
        #pragma unroll
        for (int k = 0; k < 32; ++k)
            acc1 = fmaf(__shfl(sv, k, 64), w1r[k], acc1);
        float h3 = fmaxf(acc1, 0.f);
        float oa = b2a, ob = b2b;
        #pragma unroll
        for (int k = 0; k < 32; ++k) {
            float v = __shfl(h3, (lane & 32) | k, 64);
            oa = fmaf(v, w2a[k], oa);
            ob = fmaf(v, w2b[k], ob);
        }
        oa = fmaxf(oa, 0.f); ob = fmaxf(ob, 0.f);
        float2 pr; pr.x = oa; pr.y = ob;
        reinterpret_cast<float2*>(out)[(size_t)n * 64 + lane] = pr;
    }
}

// Materialize post-BN encoder output once: out = sc*h + sh.
__global__ void k_bnout(const float* __restrict__ h, const float* __restrict__ stats,
                        fp gamma, fp beta, float* __restrict__ out)
{
    const int c = threadIdx.x & 31;
    float m  = stats[c] * (1.f / N_NODES);
    float vv = stats[32 + c] * (1.f / N_NODES) - m * m;
    float sc = gamma[c] * rsqrtf(vv + BN_EPS);
    float sh = beta[c] - m * sc;
    int i = blockIdx.x * blockDim.x + threadIdx.x;
    int stride = gridDim.x * blockDim.x;  // multiple of 32 -> (i&31)==c always
    for (; i < N_NODES * 32; i += stride) out[i] = fmaf(h[i], sc, sh);
}

// Global add-pool of one encoder layer into d_out global_rep slice (batch sorted).
// h holds PRE-BN values; pool of bn(h) = sc * sum(h) + cnt * sh.
__global__ void k_pool(const float* __restrict__ h, const int* __restrict__ gstart,
                       float* __restrict__ out, int col0,
                       const float* __restrict__ stats, fp gamma, fp beta)
{
    int g = blockIdx.x;
    int t = threadIdx.x;
    int f = t & 31, j = t >> 5;  // 8 node-groups x 32 features
    int n0 = gstart[g], n1 = gstart[g + 1];
    float s = 0.f;
    for (int n = n0 + j; n < n1; n += 8) s += h[(size_t)n * 32 + f];
    __shared__ float red[8][32];
    red[j][f] = s; __syncthreads();
    if (t < 32) {
        float tot = 0.f;
        #pragma unroll
        for (int k = 0; k < 8; ++k) tot += red[k][f];
        float m  = stats[f] * (1.f / N_NODES);
        float vv = stats[32 + f] * (1.f / N_NODES) - m * m;
        float sc = gamma[f] * rsqrtf(vv + BN_EPS);
        float sh = beta[f] - m * sc;
        out[g * (5 * HID) + col0 + f] = fmaf(tot, sc, (float)(n1 - n0) * sh);
    }
}

// ---------------- launch ----------------

extern "C" void kernel_launch(void* const* d_in, const int* in_sizes, int n_in,
                              void* d_out, int out_size, void* d_ws, size_t ws_size,
                              hipStream_t stream) {
    fp         x        = (fp)d_in[0];
    const int* edge     = (const int*)d_in[1];
    const int* batch    = (const int*)d_in[2];
    fp e0_w1 = (fp)d_in[3],  e0_b1 = (fp)d_in[4];
    fp e0_w2 = (fp)d_in[5],  e0_b2 = (fp)d_in[6];
    fp enc_w1 = (fp)d_in[7],  enc_b1 = (fp)d_in[8];
    fp enc_w2 = (fp)d_in[9],  enc_b2 = (fp)d_in[10];
    fp enc_gamma = (fp)d_in[11], enc_beta = (fp)d_in[12];
    fp dec_w1 = (fp)d_in[13], dec_b1 = (fp)d_in[14];
    fp dec_w2 = (fp)d_in[15], dec_b2 = (fp)d_in[16];
    fp dec_w2_last = (fp)d_in[17], dec_b2_last = (fp)d_in[18];
    fp dec_gamma = (fp)d_in[19], dec_beta = (fp)d_in[20];

    const int* srcp = edge;            // edge_index[0]
    const int* dstp = edge + N_EDGES;  // edge_index[1]

    float* out_enc    = (float*)d_out;                            // [200000*32]
    float* out_dec    = (float*)d_out + (size_t)N_NODES * 32;     // [200000*128]
    float* out_global = (float*)d_out + (size_t)N_NODES * 160;    // [512*160]

    // workspace carve (256B aligned)
    char* p = (char*)d_ws;
    auto alloc = [&](size_t bytes) -> void* {
        void* r = (void*)p;
        p += (bytes + 255) & ~(size_t)255;
        return r;
    };
    int*   rowptr   = (int*)alloc((N_NODES + 1) * sizeof(int));
    int*   fillpos  = (int*)alloc(N_NODES * sizeof(int));
    int*   deg      = (int*)alloc(N_NODES * sizeof(int));
    int*   chunksum = (int*)alloc(128 * sizeof(int));
    int*   chunkoff = (int*)alloc(128 * sizeof(int));
    int*   gstart   = (int*)alloc((N_GRAPHS + 1) * sizeof(int));
    float* stats    = (float*)alloc(9 * 64 * sizeof(float));
    int*   csr      = (int*)alloc((size_t)N_EDGES * sizeof(int));
    float* hbuf     = (float*)alloc((size_t)N_NODES * 32 * sizeof(float));
    float* sbuf     = (float*)alloc((size_t)N_NODES * 32 * sizeof(float));
    unsigned short* h16 = (unsigned short*)alloc((size_t)N_NODES * 32 * sizeof(unsigned short));

    hipMemsetAsync(deg, 0, N_NODES * sizeof(int), stream);
    hipMemsetAsync(stats, 0, 9 * 64 * sizeof(float), stream);

    // CSR build (fill: 2 dispatches x 2048 blocks = 8 blocks/CU full occupancy)
    k_hist2<<<512, 256, 0, stream>>>(dstp, deg);
    k_chunksum<<<NCHUNKS, 256, 0, stream>>>(deg, chunksum);
    k_scanchunks<<<1, 128, 0, stream>>>(chunksum, chunkoff, rowptr);
    k_scanfinal<<<NCHUNKS, 256, 0, stream>>>(deg, chunkoff, rowptr, fillpos);
    k_fill2<<<2048, 256, 0, stream>>>(srcp, dstp, fillpos, csr, 0);
    k_fill2<<<2048, 256, 0, stream>>>(srcp, dstp, fillpos, csr, 256);
    k_bounds<<<3, 256, 0, stream>>>(batch, gstart);

    // ---- Encoder layer 0 (pre-projected; no BN on gather input) ----
    k_proj128<<<1024, 256, 0, stream>>>(x, e0_w1, hbuf, h16);   // hbuf/h16 = y = x@w1
    k_gather8<<<2048, 256, 0, stream>>>(hbuf, h16, rowptr, csr, sbuf,
                                        nullptr, nullptr, nullptr);
    k_mlp0<<<1024, 256, 0, stream>>>(sbuf, e0_b1, e0_w2, e0_b2, hbuf, h16, stats);
    k_pool<<<N_GRAPHS, 256, 0, stream>>>(hbuf, gstart, out_global, 0,
                                         stats, enc_gamma, enc_beta);

    // ---- Encoder layers 1..4 (32 -> 32); gather applies prev layer's BN ----
    for (int i = 0; i < 4; ++i) {
        float* st_prev = stats + i * 64;          // BN stats of h currently in hbuf
        float* st      = stats + (1 + i) * 64;
        k_gather8<<<2048, 256, 0, stream>>>(hbuf, h16, rowptr, csr, sbuf,
                                            st_prev, enc_gamma + i * 32, enc_beta + i * 32);
        k_mlp32<<<1024, 256, 0, stream>>>(sbuf,
                                          enc_w1 + i * 1024, enc_b1 + i * 32,
                                          enc_w2 + i * 1024, enc_b2 + i * 32,
                                          hbuf, h16, st);
        k_pool<<<N_GRAPHS, 256, 0, stream>>>(hbuf, gstart, out_global, (1 + i) * 32,
                                             st, enc_gamma + (1 + i) * 32,
                                             enc_beta + (1 + i) * 32);
    }

    // encoded_rep = bn(enc layer 4 output)
    k_bnout<<<2048, 256, 0, stream>>>(hbuf, stats + 4 * 64,
                                      enc_gamma + 4 * 32, enc_beta + 4 * 32, out_enc);

    // ---- Decoder layers 0..3 (32 -> 32, BN) ----
    for (int i = 0; i < 4; ++i) {
        float* st_prev = (i == 0) ? (stats + 4 * 64) : (stats + (4 + i) * 64);
        fp g_prev      = (i == 0) ? (enc_gamma + 4 * 32) : (dec_gamma + (i - 1) * 32);
        fp b_prev      = (i == 0) ? (enc_beta  + 4 * 32) : (dec_beta  + (i - 1) * 32);
        float* st      = stats + (5 + i) * 64;
        k_gather8<<<2048, 256, 0, stream>>>(hbuf, h16, rowptr, csr, sbuf,
                                            st_prev, g_prev, b_prev);
        k_mlp32<<<1024, 256, 0, stream>>>(sbuf,
                                          dec_w1 + i * 1024, dec_b1 + i * 32,
                                          dec_w2 + i * 1024, dec_b2 + i * 32,
                                          hbuf, h16, st);
    }

    // ---- Decoder layer 4 (32 -> 32 -> 128, relu, no BN) ----
    k_gather8<<<2048, 256, 0, stream>>>(hbuf, h16, rowptr, csr, sbuf,
                                        stats + 8 * 64, dec_gamma + 3 * 32,
                                        dec_beta + 3 * 32);
    k_mlp_last<<<1024, 256, 0, stream>>>(sbuf,
                                         dec_w1 + 4 * 1024, dec_b1 + 4 * 32,
                                         dec_w2_last, dec_b2_last, out_dec);
}

// Round 11
// 2678.411 us; speedup vs baseline: 1.1476x; 1.0283x over previous
//
#include <hip/hip_runtime.h>
#include <hip/hip_bf16.h>
#include <hip/hip_fp16.h>
#include <string.h>

#define N_NODES  200000
#define N_EDGES  6400000
#define N_GRAPHS 512
#define DIM_IN   128
#define HID      32
#define BN_EPS   1e-5f

// chunked scan params
#define CHUNK    2048
#define NCHUNKS  98   // ceil(200000/2048)

typedef const float* fp;

// fp16 storage helpers (RNE via v_cvt_f16_f32 / v_cvt_f32_f16)
__device__ __forceinline__ unsigned short f2h(float f) {
    __half h = __float2half(f);
    unsigned short u; __builtin_memcpy(&u, &h, 2); return u;
}
__device__ __forceinline__ float2 h2f2(unsigned int u) {
    __half2 h; __builtin_memcpy(&h, &u, 4);
    return __half22float2(h);
}

// ---------------- CSR build ----------------

// LDS-binned histogram: 16 node-ranges of 12500 (50KB LDS each), 32 blocks/range.
// Round-6: grid=256 was 1 block/CU (11.7% occ, latency-bound). Round-8 verified
// grid 512 + 4-way ILP: hist2 fell out of top-5 (220 -> <190us), total -147us.
__global__ __launch_bounds__(256) void k_hist2(const int* __restrict__ dst,
                                               int* __restrict__ deg) {
    __shared__ int lh[12500];  // 50 KB
    const int grp = blockIdx.x & 15;        // node range [0,16)
    const int blk = blockIdx.x >> 4;        // edge slice [0,32)
    const int lo = grp * 12500;
    for (int j = threadIdx.x; j < 12500; j += 256) lh[j] = 0;
    __syncthreads();
    // slice = 50000 int4 = 200K edges, processed as 4 sub-segments of 12500 int4
    const int4* d4 = reinterpret_cast<const int4*>(dst) + blk * 50000;
    for (int j = threadIdx.x; j < 12500; j += 256) {
        int4 v0 = d4[j];
        int4 v1 = d4[j + 12500];
        int4 v2 = d4[j + 25000];
        int4 v3 = d4[j + 37500];
        int a;
        a = v0.x - lo; if ((unsigned)a < 12500u) atomicAdd(&lh[a], 1);
        a = v0.y - lo; if ((unsigned)a < 12500u) atomicAdd(&lh[a], 1);
        a = v0.z - lo; if ((unsigned)a < 12500u) atomicAdd(&lh[a], 1);
        a = v0.w - lo; if ((unsigned)a < 12500u) atomicAdd(&lh[a], 1);
        a = v1.x - lo; if ((unsigned)a < 12500u) atomicAdd(&lh[a], 1);
        a = v1.y - lo; if ((unsigned)a < 12500u) atomicAdd(&lh[a], 1);
        a = v1.z - lo; if ((unsigned)a < 12500u) atomicAdd(&lh[a], 1);
        a = v1.w - lo; if ((unsigned)a < 12500u) atomicAdd(&lh[a], 1);
        a = v2.x - lo; if ((unsigned)a < 12500u) atomicAdd(&lh[a], 1);
        a = v2.y - lo; if ((unsigned)a < 12500u) atomicAdd(&lh[a], 1);
        a = v2.z - lo; if ((unsigned)a < 12500u) atomicAdd(&lh[a], 1);
        a = v2.w - lo; if ((unsigned)a < 12500u) atomicAdd(&lh[a], 1);
        a = v3.x - lo; if ((unsigned)a < 12500u) atomicAdd(&lh[a], 1);
        a = v3.y - lo; if ((unsigned)a < 12500u) atomicAdd(&lh[a], 1);
        a = v3.z - lo; if ((unsigned)a < 12500u) atomicAdd(&lh[a], 1);
        a = v3.w - lo; if ((unsigned)a < 12500u) atomicAdd(&lh[a], 1);
    }
    __syncthreads();
    for (int j = threadIdx.x; j < 12500; j += 256) {
        int c = lh[j];
        if (c) atomicAdd(&deg[lo + j], c);
    }
}

__global__ void k_chunksum(const int* __restrict__ deg, int* __restrict__ chunksum) {
    __shared__ int red[256];
    int b = blockIdx.x, t = threadIdx.x;
    int base = b * CHUNK;
    int s = 0;
    for (int k = 0; k < 8; ++k) {
        int i = base + t + k * 256;
        if (i < N_NODES) s += deg[i];
    }
    red[t] = s; __syncthreads();
    for (int off = 128; off > 0; off >>= 1) {
        if (t < off) red[t] += red[t + off];
        __syncthreads();
    }
    if (t == 0) chunksum[b] = red[0];
}

__global__ void k_scanchunks(const int* __restrict__ chunksum, int* __restrict__ chunkoff,
                             int* __restrict__ rowptr) {
    __shared__ int buf[128];
    int t = threadIdx.x;  // 128 threads
    int v = (t < NCHUNKS) ? chunksum[t] : 0;
    buf[t] = v; __syncthreads();
    for (int off = 1; off < 128; off <<= 1) {
        int add = (t >= off) ? buf[t - off] : 0;
        __syncthreads();
        buf[t] += add;
        __syncthreads();
    }
    if (t < NCHUNKS) chunkoff[t] = buf[t] - v;  // exclusive
    if (t == 0) rowptr[N_NODES] = N_EDGES;      // every edge has valid dst
}

__global__ void k_scanfinal(const int* __restrict__ deg, const int* __restrict__ chunkoff,
                            int* __restrict__ rowptr, int* __restrict__ fillpos) {
    __shared__ int tsum[256];
    int b = blockIdx.x, t = threadIdx.x;
    int base = b * CHUNK + t * 8;
    int v[8]; int s = 0;
    for (int k = 0; k < 8; ++k) {
        int i = base + k;
        v[k] = (i < N_NODES) ? deg[i] : 0;
        s += v[k];
    }
    tsum[t] = s; __syncthreads();
    for (int off = 1; off < 256; off <<= 1) {
        int add = (t >= off) ? tsum[t - off] : 0;
        __syncthreads();
        tsum[t] += add;
        __syncthreads();
    }
    int run = tsum[t] - s + chunkoff[b];
    for (int k = 0; k < 8; ++k) {
        int i = base + k;
        if (i < N_NODES) { rowptr[i] = run; fillpos[i] = run; run += v[k]; }
    }
}

// Ranged fill: grp = blockIdx&7 matches the round-robin block->XCD dispatch, so
// atomics to a 100KB fillpos slice stay resident in ONE XCD's L2 (round-4:
// single-pass fill = cross-XCD ping-pong, 540us vs 300us). Round-8/9 occupancy
// curve: 2/CU=1515, 4/CU=1890, 8/CU=1780 GB/s — saturated; the 2-dispatch split
// cost ~25us (bubble+ramp). This round: ONE dispatch, 4096 blocks = 8/CU.
__global__ __launch_bounds__(256) void k_fill2(
    const int* __restrict__ src, const int* __restrict__ dst,
    int* __restrict__ fillpos, int* __restrict__ csr)
{
    const int grp = blockIdx.x & 7;
    const int blk = blockIdx.x >> 3;   // 3125-int4 slice index [0,512)
    const int lo = grp * 25000, hi = lo + 25000;
    const int4* d4 = reinterpret_cast<const int4*>(dst) + blk * 3125;
    const int4* s4 = reinterpret_cast<const int4*>(src) + blk * 3125;
    for (int j = threadIdx.x; j < 3125; j += 256) {
        int4 d = d4[j];
        int4 s = s4[j];
        if (d.x >= lo && d.x < hi) { int p = atomicAdd(&fillpos[d.x], 1); csr[p] = s.x; }
        if (d.y >= lo && d.y < hi) { int p = atomicAdd(&fillpos[d.y], 1); csr[p] = s.y; }
        if (d.z >= lo && d.z < hi) { int p = atomicAdd(&fillpos[d.z], 1); csr[p] = s.z; }
        if (d.w >= lo && d.w < hi) { int p = atomicAdd(&fillpos[d.w], 1); csr[p] = s.w; }
    }
}

__global__ void k_bounds(const int* __restrict__ batch, int* __restrict__ gstart) {
    int g = blockIdx.x * blockDim.x + threadIdx.x;
    if (g > N_GRAPHS) return;
    if (g == N_GRAPHS) { gstart[g] = N_NODES; return; }
    int lo = 0, hi = N_NODES;
    while (lo < hi) {
        int mid = (lo + hi) >> 1;
        if (batch[mid] < g) lo = mid + 1; else hi = mid;
    }
    gstart[g] = lo;
}

// ---------------- Layer-0 pre-projection: y = x @ w1  (128 -> 32) ----------------
// Round-9 counters: 162us, 553 GB/s (7%), VALUBusy 14%, occ 19.6% — latency-bound,
// one row in flight per worker then a ~740cy shfl/fma chain. Fix: 2 rows per
// iteration, all 8 loads issued upfront; w1s LDS reads shared by both rows.

__global__ __launch_bounds__(256) void k_proj128(
    const float* __restrict__ x, fp w1, float* __restrict__ y,
    unsigned short* __restrict__ y16)
{
    __shared__ float w1s[DIM_IN * 32];  // 16 KiB
    for (int i = threadIdx.x; i < DIM_IN * 32; i += 256) w1s[i] = w1[i];
    __syncthreads();
    const int lane = threadIdx.x & 63;
    const int c = lane & 31;
    const int srcBase = lane & 32;
    int worker   = (blockIdx.x * blockDim.x + threadIdx.x) >> 5;
    int nworkers = (gridDim.x * blockDim.x) >> 5;
    for (int n = 2 * worker; n < N_NODES; n += 2 * nworkers) {
        const float* xa = x + (size_t)n * DIM_IN;
        const float* xb = xa + DIM_IN;          // row n+1 (N_NODES even)
        float a0 = xa[c], a1 = xa[32 + c], a2 = xa[64 + c], a3 = xa[96 + c];
        float b0 = xb[c], b1 = xb[32 + c], b2 = xb[64 + c], b3 = xb[96 + c];
        float accA = 0.f, accB = 0.f;
        #pragma unroll
        for (int k = 0; k < 32; ++k) {
            float w0 = w1s[k * 32 + c];
            float w1v = w1s[(32 + k) * 32 + c];
            float w2v = w1s[(64 + k) * 32 + c];
            float w3v = w1s[(96 + k) * 32 + c];
            accA = fmaf(__shfl(a0, srcBase | k, 64), w0, accA);
            accB = fmaf(__shfl(b0, srcBase | k, 64), w0, accB);
            accA = fmaf(__shfl(a1, srcBase | k, 64), w1v, accA);
            accB = fmaf(__shfl(b1, srcBase | k, 64), w1v, accB);
            accA = fmaf(__shfl(a2, srcBase | k, 64), w2v, accA);
            accB = fmaf(__shfl(b2, srcBase | k, 64), w2v, accB);
            accA = fmaf(__shfl(a3, srcBase | k, 64), w3v, accA);
            accB = fmaf(__shfl(b3, srcBase | k, 64), w3v, accB);
        }
        y[(size_t)n * 32 + c] = accA;
        y16[(size_t)n * 32 + c] = f2h(accA);
        y[(size_t)(n + 1) * 32 + c] = accB;
        y16[(size_t)(n + 1) * 32 + c] = f2h(accB);
    }
}

// ---------------- Gather with BN fold (dual-row 8B loads, all-fp16) ----------------
// s[n] = sc * (h16[n] + sum_{j in N(n)} h16[j]) + (deg+1) * sh  (BN affine commutes)
// 16 lanes per node; per edge pair ONE uint2 load per lane (even edges: sub<8,
// odd: sub>=8); each lane covers channels 4q..4q+3. Self row also read from h16
// (issued before the edge loop, hh==0 half only — xor-combine would double it).

__global__ __launch_bounds__(256) void k_gather8(
    const unsigned short* __restrict__ h16,
    const int* __restrict__ rowptr, const int* __restrict__ csr,
    float* __restrict__ sout,
    const float* __restrict__ stats, fp gamma, fp beta)
{
    const int lane = threadIdx.x & 63;
    const int sub  = lane & 15;      // position in 16-lane node group
    const int q    = sub & 7;        // quarter-row slot (uint2 index in row)
    const int hh   = sub >> 3;       // 0: even edges, 1: odd edges
    const int srcBase = lane & 48;   // group base within wave
    // BN affine for this lane's 4 channels c = 4q..4q+3
    float sc0 = 1.f, sc1 = 1.f, sc2 = 1.f, sc3 = 1.f;
    float sh0 = 0.f, sh1 = 0.f, sh2 = 0.f, sh3 = 0.f;
    if (stats) {
        const int c0 = 4 * q;
        float m0 = stats[c0 + 0] * (1.f / N_NODES);
        float m1 = stats[c0 + 1] * (1.f / N_NODES);
        float m2 = stats[c0 + 2] * (1.f / N_NODES);
        float m3 = stats[c0 + 3] * (1.f / N_NODES);
        float v0 = stats[32 + c0 + 0] * (1.f / N_NODES) - m0 * m0;
        float v1 = stats[32 + c0 + 1] * (1.f / N_NODES) - m1 * m1;
        float v2 = stats[32 + c0 + 2] * (1.f / N_NODES) - m2 * m2;
        float v3 = stats[32 + c0 + 3] * (1.f / N_NODES) - m3 * m3;
        sc0 = gamma[c0 + 0] * rsqrtf(v0 + BN_EPS);
        sc1 = gamma[c0 + 1] * rsqrtf(v1 + BN_EPS);
        sc2 = gamma[c0 + 2] * rsqrtf(v2 + BN_EPS);
        sc3 = gamma[c0 + 3] * rsqrtf(v3 + BN_EPS);
        sh0 = beta[c0 + 0] - m0 * sc0;
        sh1 = beta[c0 + 1] - m1 * sc1;
        sh2 = beta[c0 + 2] - m2 * sc2;
        sh3 = beta[c0 + 3] - m3 * sc3;
    }
    const uint2* hp2 = reinterpret_cast<const uint2*>(h16);  // row = 8 uint2 (64B)
    float4* so4 = reinterpret_cast<float4*>(sout);
    int worker   = (blockIdx.x * blockDim.x + threadIdx.x) >> 4;
    int nworkers = (gridDim.x * blockDim.x) >> 4;
    for (int n = worker; n < N_NODES; n += nworkers) {
        uint2 us = hp2[(size_t)n * 8 + q];    // self row (fp16), issued early
        int e0 = rowptr[n], e1 = rowptr[n + 1];
        float2 sA = h2f2(us.x), sB = h2f2(us.y);
        float a0 = (hh == 0) ? sA.x : 0.f;
        float a1 = (hh == 0) ? sA.y : 0.f;
        float a2 = (hh == 0) ? sB.x : 0.f;
        float a3 = (hh == 0) ? sB.y : 0.f;
        int e = e0;
        while (e < e1) {
            int rem = e1 - e;
            int cnt = rem < 16 ? rem : 16;
            int myidx = (sub < cnt) ? csr[e + sub] : 0;
            if (cnt == 16) {
                int i0 = __shfl(myidx, srcBase | (0  + hh), 64);
                int i1 = __shfl(myidx, srcBase | (2  + hh), 64);
                int i2 = __shfl(myidx, srcBase | (4  + hh), 64);
                int i3 = __shfl(myidx, srcBase | (6  + hh), 64);
                int i4 = __shfl(myidx, srcBase | (8  + hh), 64);
                int i5 = __shfl(myidx, srcBase | (10 + hh), 64);
                int i6 = __shfl(myidx, srcBase | (12 + hh), 64);
                int i7 = __shfl(myidx, srcBase | (14 + hh), 64);
                uint2 u0 = hp2[(size_t)i0 * 8 + q];
                uint2 u1 = hp2[(size_t)i1 * 8 + q];
                uint2 u2 = hp2[(size_t)i2 * 8 + q];
                uint2 u3 = hp2[(size_t)i3 * 8 + q];
                uint2 u4 = hp2[(size_t)i4 * 8 + q];
                uint2 u5 = hp2[(size_t)i5 * 8 + q];
                uint2 u6 = hp2[(size_t)i6 * 8 + q];
                uint2 u7 = hp2[(size_t)i7 * 8 + q];
                float2 fA, fB;
                fA = h2f2(u0.x); fB = h2f2(u0.y);
                a0 += fA.x; a1 += fA.y; a2 += fB.x; a3 += fB.y;
                fA = h2f2(u1.x); fB = h2f2(u1.y);
                a0 += fA.x; a1 += fA.y; a2 += fB.x; a3 += fB.y;
                fA = h2f2(u2.x); fB = h2f2(u2.y);
                a0 += fA.x; a1 += fA.y; a2 += fB.x; a3 += fB.y;
                fA = h2f2(u3.x); fB = h2f2(u3.y);
                a0 += fA.x; a1 += fA.y; a2 += fB.x; a3 += fB.y;
                fA = h2f2(u4.x); fB = h2f2(u4.y);
                a0 += fA.x; a1 += fA.y; a2 += fB.x; a3 += fB.y;
                fA = h2f2(u5.x); fB = h2f2(u5.y);
                a0 += fA.x; a1 += fA.y; a2 += fB.x; a3 += fB.y;
                fA = h2f2(u6.x); fB = h2f2(u6.y);
                a0 += fA.x; a1 += fA.y; a2 += fB.x; a3 += fB.y;
                fA = h2f2(u7.x); fB = h2f2(u7.y);
                a0 += fA.x; a1 += fA.y; a2 += fB.x; a3 += fB.y;
            } else {
                int k = 0;
                for (; k + 2 <= cnt; k += 2) {
                    int i = __shfl(myidx, srcBase | (k + hh), 64);
                    uint2 u = hp2[(size_t)i * 8 + q];
                    float2 fA = h2f2(u.x), fB = h2f2(u.y);
                    a0 += fA.x; a1 += fA.y; a2 += fB.x; a3 += fB.y;
                }
                if (k < cnt) {  // odd tail: only half hh==0 contributes
                    int i = __shfl(myidx, srcBase | k, 64);
                    if (hh == 0) {
                        uint2 u = hp2[(size_t)i * 8 + q];
                        float2 fA = h2f2(u.x), fB = h2f2(u.y);
                        a0 += fA.x; a1 += fA.y; a2 += fB.x; a3 += fB.y;
                    }
                }
            }
            e += cnt;
        }
        // combine even/odd halves within the group
        a0 += __shfl_xor(a0, 8, 64);
        a1 += __shfl_xor(a1, 8, 64);
        a2 += __shfl_xor(a2, 8, 64);
        a3 += __shfl_xor(a3, 8, 64);
        // BN; write by the hh==0 half (8 lanes x 16B = full 128B row)
        float dc = (float)(e1 - e0 + 1);   // deg + 1 (self)
        float4 o;
        o.x = fmaf(a0, sc0, dc * sh0);
        o.y = fmaf(a1, sc1, dc * sh1);
        o.z = fmaf(a2, sc2, dc * sh2);
        o.w = fmaf(a3, sc3, dc * sh3);
        if (hh == 0) so4[(size_t)n * 8 + q] = o;
    }
}

// ---------------- MLP kernels (streaming, fused BN-stats) ----------------
// Write PRE-BN activation a = relu(mlp(s)) to hout (fp32) + h16out (fp16),
// accumulate per-channel sum / sum-of-squares into stats.

__global__ __launch_bounds__(256) void k_mlp32(
    const float* __restrict__ s, fp w1, fp b1, fp w2, fp b2,
    float* __restrict__ hout, unsigned short* __restrict__ h16out,
    float* __restrict__ stats)
{
    const int lane = threadIdx.x & 63;
    const int c = lane & 31;
    const int srcBase = lane & 32;
    float w1r[32], w2r[32];
    #pragma unroll
    for (int k = 0; k < 32; ++k) {
        w1r[k] = w1[k * 32 + c];
        w2r[k] = w2[k * 32 + c];
    }
    const float b1c = b1[c];
    const float b2c = b2[c];
    int worker   = (blockIdx.x * blockDim.x + threadIdx.x) >> 5;
    int nworkers = (gridDim.x * blockDim.x) >> 5;
    float s1 = 0.f, s2 = 0.f;
    for (int n = worker; n < N_NODES; n += nworkers) {
        float sv = s[(size_t)n * 32 + c];
        float acc1 = b1c;
        #pragma unroll
        for (int k = 0; k < 32; ++k)
            acc1 = fmaf(__shfl(sv, srcBase | k, 64), w1r[k], acc1);
        float h3 = fmaxf(acc1, 0.f);
        float acc2 = b2c;
        #pragma unroll
        for (int k = 0; k < 32; ++k)
            acc2 = fmaf(__shfl(h3, srcBase | k, 64), w2r[k], acc2);
        float a = fmaxf(acc2, 0.f);
        hout[(size_t)n * 32 + c] = a;
        h16out[(size_t)n * 32 + c] = f2h(a);
        s1 += a; s2 += a * a;
    }
    s1 += __shfl_xor(s1, 32, 64);
    s2 += __shfl_xor(s2, 32, 64);
    __shared__ float ls1[4][32], ls2[4][32];
    int w = threadIdx.x >> 6;
    if ((threadIdx.x & 32) == 0) { ls1[w][c] = s1; ls2[w][c] = s2; }
    __syncthreads();
    if (threadIdx.x < 32) {
        float t1 = ls1[0][c] + ls1[1][c] + ls1[2][c] + ls1[3][c];
        float t2 = ls2[0][c] + ls2[1][c] + ls2[2][c] + ls2[3][c];
        atomicAdd(&stats[c], t1);
        atomicAdd(&stats[32 + c], t2);
    }
}

// layer-0 variant: s already = (x+agg)@w1, so stage 1 is elementwise.
__global__ __launch_bounds__(256) void k_mlp0(
    const float* __restrict__ s, fp b1, fp w2, fp b2,
    float* __restrict__ hout, unsigned short* __restrict__ h16out,
    float* __restrict__ stats)
{
    const int lane = threadIdx.x & 63;
    const int c = lane & 31;
    const int srcBase = lane & 32;
    float w2r[32];
    #pragma unroll
    for (int k = 0; k < 32; ++k) w2r[k] = w2[k * 32 + c];
    const float b1c = b1[c];
    const float b2c = b2[c];
    int worker   = (blockIdx.x * blockDim.x + threadIdx.x) >> 5;
    int nworkers = (gridDim.x * blockDim.x) >> 5;
    float s1 = 0.f, s2 = 0.f;
    for (int n = worker; n < N_NODES; n += nworkers) {
        float sv = s[(size_t)n * 32 + c];
        float h3 = fmaxf(sv + b1c, 0.f);
        float acc2 = b2c;
        #pragma unroll
        for (int k = 0; k < 32; ++k)
            acc2 = fmaf(__shfl(h3, srcBase | k, 64), w2r[k], acc2);
        float a = fmaxf(acc2, 0.f);
        hout[(size_t)n * 32 + c] = a;
        h16out[(size_t)n * 32 + c] = f2h(a);
        s1 += a; s2 += a * a;
    }
    s1 += __shfl_xor(s1, 32, 64);
    s2 += __shfl_xor(s2, 32, 64);
    __shared__ float ls1[4][32], ls2[4][32];
    int w = threadIdx.x >> 6;
    if ((threadIdx.x & 32) == 0) { ls1[w][c] = s1; ls2[w][c] = s2; }
    __syncthreads();
    if (threadIdx.x < 32) {
        float t1 = ls1[0][c] + ls1[1][c] + ls1[2][c] + ls1[3][c];
        float t2 = ls2[0][c] + ls2[1][c] + ls2[2][c] + ls2[3][c];
        atomicAdd(&stats[c], t1);
        atomicAdd(&stats[32 + c], t2);
    }
}

// decoder last: out = relu(relu(s@w1+b1)@w2_last+b2_last), 32 -> 32 -> 128.
__global__ __launch_bounds__(256) void k_mlp_last(
    const float* __restrict__ s, fp w1, fp b1, fp w2 /*[32][128]*/, fp b2,
    float* __restrict__ out)
{
    const int lane = threadIdx.x & 63;
    const int c = lane & 31;
    float w1r[32], w2a[32], w2b[32];
    #pragma unroll
    for (int k = 0; k < 32; ++k) {
        w1r[k] = w1[k * 32 + c];
        w2a[k] = w2[k * 128 + 2 * lane];
        w2b[k] = w2[k * 128 + 2 * lane + 1];
    }
    const float b1c = b1[c];
    const float b2a = b2[2 * lane];
    const float b2b = b2[2 * lane + 1];
    int worker   = (blockIdx.x * blockDim.x + threadIdx.x) >> 6;
    int nworkers = (gridDim.x * blockDim.x) >> 6;
    for (int n = worker; n < N_NODES; n += nworkers) {
        float sv = s[(size_t)n * 32 + c];  // duplicated across halves
        float acc1 = b1c;
        #pragma unroll
        for (int k = 0; k < 32; ++k)
            acc1 = fmaf(__shfl(sv, k, 64), w1r[k], acc1);
        float h3 = fmaxf(acc1, 0.f);
        float oa = b2a, ob = b2b;
        #pragma unroll
        for (int k = 0; k < 32; ++k) {
            float v = __shfl(h3, (lane & 32) | k, 64);
            oa = fmaf(v, w2a[k], oa);
            ob = fmaf(v, w2b[k], ob);
        }
        oa = fmaxf(oa, 0.f); ob = fmaxf(ob, 0.f);
        float2 pr; pr.x = oa; pr.y = ob;
        reinterpret_cast<float2*>(out)[(size_t)n * 64 + lane] = pr;
    }
}

// Materialize post-BN encoder output once: out = sc*h + sh.
__global__ void k_bnout(const float* __restrict__ h, const float* __restrict__ stats,
                        fp gamma, fp beta, float* __restrict__ out)
{
    const int c = threadIdx.x & 31;
    float m  = stats[c] * (1.f / N_NODES);
    float vv = stats[32 + c] * (1.f / N_NODES) - m * m;
    float sc = gamma[c] * rsqrtf(vv + BN_EPS);
    float sh = beta[c] - m * sc;
    int i = blockIdx.x * blockDim.x + threadIdx.x;
    int stride = gridDim.x * blockDim.x;  // multiple of 32 -> (i&31)==c always
    for (; i < N_NODES * 32; i += stride) out[i] = fmaf(h[i], sc, sh);
}

// Global add-pool of one encoder layer into d_out global_rep slice (batch sorted).
// h holds PRE-BN values; pool of bn(h) = sc * sum(h) + cnt * sh.
__global__ void k_pool(const float* __restrict__ h, const int* __restrict__ gstart,
                       float* __restrict__ out, int col0,
                       const float* __restrict__ stats, fp gamma, fp beta)
{
    int g = blockIdx.x;
    int t = threadIdx.x;
    int f = t & 31, j = t >> 5;  // 8 node-groups x 32 features
    int n0 = gstart[g], n1 = gstart[g + 1];
    float s = 0.f;
    for (int n = n0 + j; n < n1; n += 8) s += h[(size_t)n * 32 + f];
    __shared__ float red[8][32];
    red[j][f] = s; __syncthreads();
    if (t < 32) {
        float tot = 0.f;
        #pragma unroll
        for (int k = 0; k < 8; ++k) tot += red[k][f];
        float m  = stats[f] * (1.f / N_NODES);
        float vv = stats[32 + f] * (1.f / N_NODES) - m * m;
        float sc = gamma[f] * rsqrtf(vv + BN_EPS);
        float sh = beta[f] - m * sc;
        out[g * (5 * HID) + col0 + f] = fmaf(tot, sc, (float)(n1 - n0) * sh);
    }
}

// ---------------- launch ----------------

extern "C" void kernel_launch(void* const* d_in, const int* in_sizes, int n_in,
                              void* d_out, int out_size, void* d_ws, size_t ws_size,
                              hipStream_t stream) {
    fp         x        = (fp)d_in[0];
    const int* edge     = (const int*)d_in[1];
    const int* batch    = (const int*)d_in[2];
    fp e0_w1 = (fp)d_in[3],  e0_b1 = (fp)d_in[4];
    fp e0_w2 = (fp)d_in[5],  e0_b2 = (fp)d_in[6];
    fp enc_w1 = (fp)d_in[7],  enc_b1 = (fp)d_in[8];
    fp enc_w2 = (fp)d_in[9],  enc_b2 = (fp)d_in[10];
    fp enc_gamma = (fp)d_in[11], enc_beta = (fp)d_in[12];
    fp dec_w1 = (fp)d_in[13], dec_b1 = (fp)d_in[14];
    fp dec_w2 = (fp)d_in[15], dec_b2 = (fp)d_in[16];
    fp dec_w2_last = (fp)d_in[17], dec_b2_last = (fp)d_in[18];
    fp dec_gamma = (fp)d_in[19], dec_beta = (fp)d_in[20];

    const int* srcp = edge;            // edge_index[0]
    const int* dstp = edge + N_EDGES;  // edge_index[1]

    float* out_enc    = (float*)d_out;                            // [200000*32]
    float* out_dec    = (float*)d_out + (size_t)N_NODES * 32;     // [200000*128]
    float* out_global = (float*)d_out + (size_t)N_NODES * 160;    // [512*160]

    // workspace carve (256B aligned)
    char* p = (char*)d_ws;
    auto alloc = [&](size_t bytes) -> void* {
        void* r = (void*)p;
        p += (bytes + 255) & ~(size_t)255;
        return r;
    };
    int*   rowptr   = (int*)alloc((N_NODES + 1) * sizeof(int));
    int*   fillpos  = (int*)alloc(N_NODES * sizeof(int));
    int*   deg      = (int*)alloc(N_NODES * sizeof(int));
    int*   chunksum = (int*)alloc(128 * sizeof(int));
    int*   chunkoff = (int*)alloc(128 * sizeof(int));
    int*   gstart   = (int*)alloc((N_GRAPHS + 1) * sizeof(int));
    float* stats    = (float*)alloc(9 * 64 * sizeof(float));
    int*   csr      = (int*)alloc((size_t)N_EDGES * sizeof(int));
    float* hbuf     = (float*)alloc((size_t)N_NODES * 32 * sizeof(float));
    float* sbuf     = (float*)alloc((size_t)N_NODES * 32 * sizeof(float));
    unsigned short* h16 = (unsigned short*)alloc((size_t)N_NODES * 32 * sizeof(unsigned short));

    hipMemsetAsync(deg, 0, N_NODES * sizeof(int), stream);
    hipMemsetAsync(stats, 0, 9 * 64 * sizeof(float), stream);

    // CSR build
    k_hist2<<<512, 256, 0, stream>>>(dstp, deg);
    k_chunksum<<<NCHUNKS, 256, 0, stream>>>(deg, chunksum);
    k_scanchunks<<<1, 128, 0, stream>>>(chunksum, chunkoff, rowptr);
    k_scanfinal<<<NCHUNKS, 256, 0, stream>>>(deg, chunkoff, rowptr, fillpos);
    k_fill2<<<4096, 256, 0, stream>>>(srcp, dstp, fillpos, csr);
    k_bounds<<<3, 256, 0, stream>>>(batch, gstart);

    // ---- Encoder layer 0 (pre-projected; no BN on gather input) ----
    k_proj128<<<1024, 256, 0, stream>>>(x, e0_w1, hbuf, h16);   // hbuf/h16 = y = x@w1
    k_gather8<<<2048, 256, 0, stream>>>(h16, rowptr, csr, sbuf,
                                        nullptr, nullptr, nullptr);
    k_mlp0<<<1024, 256, 0, stream>>>(sbuf, e0_b1, e0_w2, e0_b2, hbuf, h16, stats);
    k_pool<<<N_GRAPHS, 256, 0, stream>>>(hbuf, gstart, out_global, 0,
                                         stats, enc_gamma, enc_beta);

    // ---- Encoder layers 1..4 (32 -> 32); gather applies prev layer's BN ----
    for (int i = 0; i < 4; ++i) {
        float* st_prev = stats + i * 64;          // BN stats of h currently in h16
        float* st      = stats + (1 + i) * 64;
        k_gather8<<<2048, 256, 0, stream>>>(h16, rowptr, csr, sbuf,
                                            st_prev, enc_gamma + i * 32, enc_beta + i * 32);
        k_mlp32<<<1024, 256, 0, stream>>>(sbuf,
                                          enc_w1 + i * 1024, enc_b1 + i * 32,
                                          enc_w2 + i * 1024, enc_b2 + i * 32,
                                          hbuf, h16, st);
        k_pool<<<N_GRAPHS, 256, 0, stream>>>(hbuf, gstart, out_global, (1 + i) * 32,
                                             st, enc_gamma + (1 + i) * 32,
                                             enc_beta + (1 + i) * 32);
    }

    // encoded_rep = bn(enc layer 4 output)
    k_bnout<<<2048, 256, 0, stream>>>(hbuf, stats + 4 * 64,
                                      enc_gamma + 4 * 32, enc_beta + 4 * 32, out_enc);

    // ---- Decoder layers 0..3 (32 -> 32, BN) ----
    for (int i = 0; i < 4; ++i) {
        float* st_prev = (i == 0) ? (stats + 4 * 64) : (stats + (4 + i) * 64);
        fp g_prev      = (i == 0) ? (enc_gamma + 4 * 32) : (dec_gamma + (i - 1) * 32);
        fp b_prev      = (i == 0) ? (enc_beta  + 4 * 32) : (dec_beta  + (i - 1) * 32);
        float* st      = stats + (5 + i) * 64;
        k_gather8<<<2048, 256, 0, stream>>>(h16, rowptr, csr, sbuf,
                                            st_prev, g_prev, b_prev);
        k_mlp32<<<1024, 256, 0, stream>>>(sbuf,
                                          dec_w1 + i * 1024, dec_b1 + i * 32,
                                          dec_w2 + i * 1024, dec_b2 + i * 32,
                                          hbuf, h16, st);
    }

    // ---- Decoder layer 4 (32 -> 32 -> 128, relu, no BN) ----
    k_gather8<<<2048, 256, 0, stream>>>(h16, rowptr, csr, sbuf,
                                        stats + 8 * 64, dec_gamma + 3 * 32,
                                        dec_beta + 3 * 32);
    k_mlp_last<<<1024, 256, 0, stream>>>(sbuf,
                                         dec_w1 + 4 * 1024, dec_b1 + 4 * 32,
                                         dec_w2_last, dec_b2_last, out_dec);
}